// Round 1
// 600.146 us; speedup vs baseline: 1.0758x; 1.0758x over previous
//
#include <hip/hip_runtime.h>
#include <hip/hip_bf16.h>

// ---------------------------------------------------------------------------
// 2-layer GraphSAGE on MI355X. Round 5: XCD-partitioned CSR scatter.
//   - k_scatter was 130us/dispatch with WRITE_SIZE=105MB for a 6.4MB payload:
//     random 4B stores from all 8 XCDs -> partially-dirty line copies in 8
//     incoherent L2s -> one 64B HBM writeback per store.
//   - New scatter: grid = 8 partitions x 256 slices. Block b scans edge slice
//     (b>>3) and processes only edges with dst in node-partition (b&7).
//     With round-robin blockIdx->XCD (measured m09), all writers of an ssrc
//     line sit on one XCD -> stores merge in its L2 -> ~6.4MB writebacks.
//     Correct regardless of the actual XCD mapping (partitions x slices tile
//     the edge set exactly once); the mapping only affects locality.
//   - Everything else unchanged from Round 4 (MFMA bf16 GEMMs, fused epilogue).
// ---------------------------------------------------------------------------

#define NFEAT 128

typedef __bf16 bf16x8 __attribute__((ext_vector_type(8)));
typedef float  f32x4  __attribute__((ext_vector_type(4)));

static __device__ inline unsigned short f2bf(float f) {
    union { float f; unsigned int u; } v; v.f = f;
    unsigned int u = v.u;
    unsigned int r = (u + 0x7FFFu + ((u >> 16) & 1u)) >> 16;   // RNE
    return (unsigned short)r;
}
static __device__ inline float bf2f(unsigned short h) {
    union { unsigned int u; float f; } v; v.u = ((unsigned int)h) << 16;
    return v.f;
}

__global__ __launch_bounds__(256) void k_deg(const int* __restrict__ dst,
                                             int* __restrict__ deg, int E) {
    int e = blockIdx.x * 256 + threadIdx.x;
    if (e < E) atomicAdd(&deg[dst[e]], 1);
}

// ---- 3-kernel scan ---------------------------------------------------------
__global__ __launch_bounds__(256) void k_scan1(const int* __restrict__ deg,
                                               int* __restrict__ escan,
                                               int* __restrict__ bsum, int n) {
    __shared__ int ws4[4];
    int tid = threadIdx.x;
    int base = blockIdx.x * 1024 + tid * 4;
    int d[4];
    #pragma unroll
    for (int j = 0; j < 4; ++j) d[j] = (base + j < n) ? deg[base + j] : 0;
    int s = d[0] + d[1] + d[2] + d[3];
    int lane = tid & 63, wid = tid >> 6;
    int incl = s;
    #pragma unroll
    for (int off = 1; off < 64; off <<= 1) {
        int t = __shfl_up(incl, off, 64);
        if (lane >= off) incl += t;
    }
    if (lane == 63) ws4[wid] = incl;
    __syncthreads();
    int wbase = 0;
    #pragma unroll
    for (int w = 0; w < 4; ++w) if (w < wid) wbase += ws4[w];
    int run = wbase + incl - s;
    #pragma unroll
    for (int j = 0; j < 4; ++j) {
        if (base + j < n) escan[base + j] = run;
        run += d[j];
    }
    if (tid == 255) bsum[blockIdx.x] = run;
}

__global__ __launch_bounds__(1024) void k_scan2(int* __restrict__ bsum, int nb) {
    __shared__ int ws16[16];
    int tid = threadIdx.x;
    int lane = tid & 63, wid = tid >> 6;
    int v = (tid < nb) ? bsum[tid] : 0;
    int incl = v;
    #pragma unroll
    for (int off = 1; off < 64; off <<= 1) {
        int t = __shfl_up(incl, off, 64);
        if (lane >= off) incl += t;
    }
    if (lane == 63) ws16[wid] = incl;
    __syncthreads();
    int wbase = 0;
    for (int w = 0; w < 16; ++w) if (w < wid) wbase += ws16[w];
    if (tid < nb) bsum[tid] = wbase + incl - v;   // exclusive
}

__global__ __launch_bounds__(256) void k_scan3(const int* __restrict__ deg,
                                               const int* __restrict__ escan,
                                               const int* __restrict__ bsum,
                                               int* __restrict__ offs,
                                               int* __restrict__ cursor,
                                               float* __restrict__ invd, int n) {
    int tid = threadIdx.x;
    int base = blockIdx.x * 1024 + tid * 4;
    int bb = bsum[blockIdx.x];
    #pragma unroll
    for (int j = 0; j < 4; ++j) {
        int i = base + j;
        if (i < n) {
            int d = deg[i];
            int off = escan[i] + bb;
            offs[i] = off;
            cursor[i] = off;
            invd[i] = 1.0f / fmaxf((float)d, 1.0f);
            if (i == n - 1) offs[n] = off + d;
        }
    }
}

// ---- x -> bf16 -------------------------------------------------------------
__global__ __launch_bounds__(256) void k_cvt(const float* __restrict__ x,
                                             unsigned short* __restrict__ xb,
                                             int total4) {
    int i = blockIdx.x * 256 + threadIdx.x;
    if (i >= total4) return;
    float4 v = *(const float4*)(x + (size_t)i * 4);
    ushort4 o;
    o.x = f2bf(v.x); o.y = f2bf(v.y); o.z = f2bf(v.z); o.w = f2bf(v.w);
    *(ushort4*)(xb + (size_t)i * 4) = o;
}

// ---- weight pre-swizzle into B-fragment-linear layout ----------------------
// wb[((ks*8+ct)*64+lane)*8 + j] = W[ks*32+(lane>>4)*8+j][ct*16+(lane&15)]
__global__ __launch_bounds__(256) void k_wprep1(const float* __restrict__ Ws,
                                                const float* __restrict__ Wn,
                                                unsigned short* __restrict__ wb) {
    int idx = blockIdx.x * 256 + threadIdx.x;        // 8*8*64*8 = 32768
    if (idx >= 32768) return;
    int j = idx & 7, lane = (idx >> 3) & 63, ct = (idx >> 9) & 7, ks = idx >> 12;
    int k = ks * 32 + ((lane >> 4) & 3) * 8 + j;     // 0..255
    int n = ct * 16 + (lane & 15);                   // 0..127
    float v = (k < 128) ? Ws[k * 128 + n] : Wn[(k - 128) * 128 + n];
    wb[idx] = f2bf(v);
}

__global__ __launch_bounds__(256) void k_wprep2(const float* __restrict__ Ws,
                                                const float* __restrict__ Wn,
                                                unsigned short* __restrict__ wb) {
    int idx = blockIdx.x * 256 + threadIdx.x;        // 4*8*64*8 = 16384
    if (idx >= 16384) return;
    int j = idx & 7, lane = (idx >> 3) & 63, ct = (idx >> 9) & 7, ks = idx >> 12;
    int k = ks * 32 + ((lane >> 4) & 3) * 8 + j;     // 0..127
    int n = ct * 16 + (lane & 15);                   // 0..127; <64 Ws, >=64 Wn
    float v = (n < 64) ? Ws[k * 64 + n] : Wn[k * 64 + (n - 64)];
    wb[idx] = f2bf(v);
}

// ---- XCD-partitioned CSR scatter -------------------------------------------
// grid = 8 * NSLICE blocks. part = blockIdx&7 owns nodes [part*P, part*P+P);
// slice = blockIdx>>3 owns edges [slice*per, slice*per+per). With round-robin
// block->XCD placement all stores to a given ssrc line come from ONE XCD's
// L2, so 4B stores merge before writeback instead of 1 line/store.
__global__ __launch_bounds__(256) void k_scatter(const int* __restrict__ src,
                                                 const int* __restrict__ dst,
                                                 int* __restrict__ cursor,
                                                 int* __restrict__ ssrc,
                                                 int E, int P) {
    int part = blockIdx.x & 7;
    int slice = blockIdx.x >> 3;
    int nslices = gridDim.x >> 3;
    int per = (E + nslices - 1) / nslices;
    int beg = slice * per;
    int end = beg + per; if (end > E) end = E;
    int lo = part * P;
    int hi = lo + P;
    for (int e = beg + threadIdx.x; e < end; e += 256) {
        int d = dst[e];
        if (d >= lo && d < hi) {
            int pos = atomicAdd(&cursor[d], 1);
            ssrc[pos] = src[e];
        }
    }
}

// ---- layer-1 aggregation: gather bf16 x rows, mean -> aggb (bf16, N x 128) -
__global__ __launch_bounds__(256) void k_agg1(const unsigned short* __restrict__ xb,
                                              const int* __restrict__ offs,
                                              const int* __restrict__ ssrc,
                                              const float* __restrict__ invd,
                                              unsigned short* __restrict__ aggb,
                                              int n) {
    int node = blockIdx.x * 8 + (threadIdx.x >> 5);
    if (node >= n) return;
    int lane = threadIdx.x & 31;           // 32 lanes x 4 bf16 = 128 feats
    int beg = offs[node], end = offs[node + 1];
    float a0 = 0.f, a1 = 0.f, a2 = 0.f, a3 = 0.f;
    for (int e = beg; e < end; ++e) {
        int s = ssrc[e];
        ushort4 v = *(const ushort4*)(xb + (size_t)s * NFEAT + lane * 4);
        a0 += bf2f(v.x); a1 += bf2f(v.y); a2 += bf2f(v.z); a3 += bf2f(v.w);
    }
    float iv = invd[node];
    ushort4 o;
    o.x = f2bf(a0 * iv); o.y = f2bf(a1 * iv);
    o.z = f2bf(a2 * iv); o.w = f2bf(a3 * iv);
    *(ushort4*)(aggb + (size_t)node * NFEAT + lane * 4) = o;
}

// ---- layer-1 MFMA GEMM: [xb||aggb] @ Wb1 + b1 -> h1, h1r, h1rb -------------
__global__ __launch_bounds__(256) void k_mm1(const unsigned short* __restrict__ xb,
                                             const unsigned short* __restrict__ aggb,
                                             const unsigned short* __restrict__ wb,
                                             const float* __restrict__ bias,
                                             float* __restrict__ h1,
                                             float* __restrict__ h1r,
                                             unsigned short* __restrict__ h1rb,
                                             int M) {
    int wave = threadIdx.x >> 6, lane = threadIdx.x & 63;
    int rowbase = blockIdx.x * 64 + wave * 16;
    f32x4 acc[8];
    #pragma unroll
    for (int ct = 0; ct < 8; ++ct) acc[ct] = (f32x4){0.f, 0.f, 0.f, 0.f};

    int arow = rowbase + (lane & 15);
    if (arow >= M) arow = M - 1;
    int kq = ((lane >> 4) & 3) * 8;

    #pragma unroll 1
    for (int ks = 0; ks < 8; ++ks) {
        const unsigned short* Ap = (ks < 4) ? xb : aggb;
        bf16x8 a = *(const bf16x8*)(Ap + (size_t)arow * 128 + (ks & 3) * 32 + kq);
        const unsigned short* wp = wb + ((size_t)ks * 8 * 64 + lane) * 8;
        #pragma unroll
        for (int ct = 0; ct < 8; ++ct) {
            bf16x8 b = *(const bf16x8*)(wp + (size_t)ct * 512);
            acc[ct] = __builtin_amdgcn_mfma_f32_16x16x32_bf16(a, b, acc[ct], 0, 0, 0);
        }
    }

    int r0 = rowbase + ((lane >> 4) & 3) * 4;
    int col0 = lane & 15;
    #pragma unroll
    for (int ct = 0; ct < 8; ++ct) {
        int col = ct * 16 + col0;
        float bv = bias[col];
        #pragma unroll
        for (int i = 0; i < 4; ++i) {
            int row = r0 + i;
            if (row < M) {
                float v = acc[ct][i] + bv;
                float vr = fmaxf(v, 0.f);
                size_t o = (size_t)row * 128 + col;
                h1[o] = v;
                h1r[o] = vr;
                h1rb[o] = f2bf(vr);
            }
        }
    }
}

// ---- layer-2 MFMA GEMM: h1rb @ [Ws2|Wn2] -> s2 (f32), p2b (bf16) -----------
__global__ __launch_bounds__(256) void k_mm2(const unsigned short* __restrict__ h1rb,
                                             const unsigned short* __restrict__ wb,
                                             float* __restrict__ s2,
                                             unsigned short* __restrict__ p2b,
                                             int M) {
    int wave = threadIdx.x >> 6, lane = threadIdx.x & 63;
    int rowbase = blockIdx.x * 64 + wave * 16;
    f32x4 acc[8];
    #pragma unroll
    for (int ct = 0; ct < 8; ++ct) acc[ct] = (f32x4){0.f, 0.f, 0.f, 0.f};

    int arow = rowbase + (lane & 15);
    if (arow >= M) arow = M - 1;
    int kq = ((lane >> 4) & 3) * 8;

    #pragma unroll 1
    for (int ks = 0; ks < 4; ++ks) {
        bf16x8 a = *(const bf16x8*)(h1rb + (size_t)arow * 128 + ks * 32 + kq);
        const unsigned short* wp = wb + ((size_t)ks * 8 * 64 + lane) * 8;
        #pragma unroll
        for (int ct = 0; ct < 8; ++ct) {
            bf16x8 b = *(const bf16x8*)(wp + (size_t)ct * 512);
            acc[ct] = __builtin_amdgcn_mfma_f32_16x16x32_bf16(a, b, acc[ct], 0, 0, 0);
        }
    }

    int r0 = rowbase + ((lane >> 4) & 3) * 4;
    int col0 = lane & 15;
    #pragma unroll
    for (int ct = 0; ct < 8; ++ct) {
        int col = ct * 16 + col0;
        #pragma unroll
        for (int i = 0; i < 4; ++i) {
            int row = r0 + i;
            if (row < M) {
                float v = acc[ct][i];
                if (col < 64)
                    s2[(size_t)row * 64 + col] = v;
                else
                    p2b[(size_t)row * 64 + (col - 64)] = f2bf(v);
            }
        }
    }
}

// ---- layer-2 aggregation + epilogue: h2 = s2 + inv*sum(p2b[src]) + b2 ------
__global__ __launch_bounds__(256) void k_agg2(const unsigned short* __restrict__ p2b,
                                              const int* __restrict__ offs,
                                              const int* __restrict__ ssrc,
                                              const float* __restrict__ invd,
                                              const float* __restrict__ s2,
                                              const float* __restrict__ b2,
                                              float* __restrict__ h2a,
                                              float* __restrict__ h2b, int n) {
    int node = blockIdx.x * 16 + (threadIdx.x >> 4);
    if (node >= n) return;
    int lane = threadIdx.x & 15;           // 16 lanes x 4 bf16 = 64 feats
    int beg = offs[node], end = offs[node + 1];
    float a0 = 0.f, a1 = 0.f, a2 = 0.f, a3 = 0.f;
    for (int e = beg; e < end; ++e) {
        int s = ssrc[e];
        ushort4 v = *(const ushort4*)(p2b + (size_t)s * 64 + lane * 4);
        a0 += bf2f(v.x); a1 += bf2f(v.y); a2 += bf2f(v.z); a3 += bf2f(v.w);
    }
    float iv = invd[node];
    float4 sv = *(const float4*)(s2 + (size_t)node * 64 + lane * 4);
    float4 bv = *(const float4*)(b2 + lane * 4);
    float4 r = make_float4(sv.x + a0 * iv + bv.x, sv.y + a1 * iv + bv.y,
                           sv.z + a2 * iv + bv.z, sv.w + a3 * iv + bv.w);
    *(float4*)(h2a + (size_t)node * 64 + lane * 4) = r;
    *(float4*)(h2b + (size_t)node * 64 + lane * 4) = r;
}

static inline size_t align256(size_t x) { return (x + 255) & ~(size_t)255; }

extern "C" void kernel_launch(void* const* d_in, const int* in_sizes, int n_in,
                              void* d_out, int out_size, void* d_ws, size_t ws_size,
                              hipStream_t stream) {
    const float* x   = (const float*)d_in[0];
    const float* Ws1 = (const float*)d_in[1];
    const float* Wn1 = (const float*)d_in[2];
    const float* b1  = (const float*)d_in[3];
    const float* Ws2 = (const float*)d_in[4];
    const float* Wn2 = (const float*)d_in[5];
    const float* b2  = (const float*)d_in[6];
    const int* src   = (const int*)d_in[7];
    const int* dst   = (const int*)d_in[8];

    int E = in_sizes[7];
    int N = in_sizes[0] / NFEAT;

    float* out = (float*)d_out;
    float* h2a = out;                         // h2 (copy 1), N x 64
    float* h1  = out + (size_t)N * 64;        // h1, N x 128
    float* h1r = out + (size_t)N * 192;       // relu(h1), N x 128
    float* h2b = out + (size_t)N * 320;       // h2 (copy 2), N x 64

    char* ws = (char*)d_ws;
    size_t off = 0;
    int*   deg    = (int*)(ws + off);  off = align256(off + (size_t)4 * N);
    int*   offs   = (int*)(ws + off);  off = align256(off + (size_t)4 * (N + 1));
    int*   cursor = (int*)(ws + off);  off = align256(off + (size_t)4 * N);
    float* invd   = (float*)(ws + off); off = align256(off + (size_t)4 * N);
    int*   escan  = (int*)(ws + off);  off = align256(off + (size_t)4 * N);
    int*   bsum   = (int*)(ws + off);  off = align256(off + (size_t)4 * 1024);
    int*   ssrc   = (int*)(ws + off);  off = align256(off + (size_t)4 * E);
    unsigned short* wb1 = (unsigned short*)(ws + off); off = align256(off + 2 * 32768);
    unsigned short* wb2 = (unsigned short*)(ws + off); off = align256(off + 2 * 16384);
    // region1: xb (N*128 bf16 = 25.6 MB) aliases s2 (N*64 f32 = 25.6 MB);
    //          xb dead after k_mm1, s2 written by k_mm2.
    unsigned short* xb = (unsigned short*)(ws + off);
    float*          s2 = (float*)(ws + off);
    off = align256(off + (size_t)N * NFEAT * 2);
    // region2: aggb (N*128 bf16) aliases p2b (N*64 bf16);
    //          aggb dead after k_mm1, p2b written by k_mm2.
    unsigned short* aggb = (unsigned short*)(ws + off);
    unsigned short* p2b  = (unsigned short*)(ws + off);
    off = align256(off + (size_t)N * NFEAT * 2);
    unsigned short* h1rb = (unsigned short*)(ws + off);
    off += (size_t)N * NFEAT * 2;

    int nb = (N + 1023) / 1024;
    int P = (N + 7) / 8;                      // nodes per XCD partition

    hipMemsetAsync(deg, 0, (size_t)4 * N, stream);
    k_deg<<<(E + 255) / 256, 256, 0, stream>>>(dst, deg, E);
    k_scan1<<<nb, 256, 0, stream>>>(deg, escan, bsum, N);
    k_scan2<<<1, 1024, 0, stream>>>(bsum, nb);
    k_scan3<<<nb, 256, 0, stream>>>(deg, escan, bsum, offs, cursor, invd, N);
    k_cvt<<<(N * 32 + 255) / 256, 256, 0, stream>>>(x, xb, N * 32);
    k_wprep1<<<128, 256, 0, stream>>>(Ws1, Wn1, wb1);
    k_wprep2<<<64, 256, 0, stream>>>(Ws2, Wn2, wb2);
    // 8 partitions x 256 slices; slice scanned by all 8 partition-blocks.
    k_scatter<<<8 * 256, 256, 0, stream>>>(src, dst, cursor, ssrc, E, P);

    k_agg1<<<(N + 7) / 8, 256, 0, stream>>>(xb, offs, ssrc, invd, aggb, N);
    k_mm1<<<(N + 63) / 64, 256, 0, stream>>>(xb, aggb, wb1, b1, h1, h1r, h1rb, N);
    k_mm2<<<(N + 63) / 64, 256, 0, stream>>>(h1rb, wb2, s2, p2b, N);
    k_agg2<<<(N + 15) / 16, 256, 0, stream>>>(p2b, offs, ssrc, invd, s2, b2, h2a, h2b, N);
}

// Round 2
// 545.914 us; speedup vs baseline: 1.1827x; 1.0993x over previous
//
#include <hip/hip_runtime.h>
#include <hip/hip_bf16.h>

// ---------------------------------------------------------------------------
// 2-layer GraphSAGE on MI355X. Round 6: MLP-4 gather loops in k_agg1/k_agg2.
//   - Round-5 recap: XCD-partitioned scatter removed the 105MB writeback storm
//     (646 -> 600us); top-5 is now harness ws-poison fills (~120us, not ours).
//   - Remaining theory: agg kernels are LATENCY-bound, not BW-bound. The
//     per-edge loop was: load ssrc[e] -> dependent 256B gather -> accumulate,
//     i.e. ~deg sequential L3 round-trips per node (MLP=1).
//   - This round: unroll the edge loop by 4 with two independent accumulator
//     sets -> 4 gathers in flight per 32-lane group. Pure reassociation of a
//     sum; no layout/precision change anywhere else.
// ---------------------------------------------------------------------------

#define NFEAT 128

typedef __bf16 bf16x8 __attribute__((ext_vector_type(8)));
typedef float  f32x4  __attribute__((ext_vector_type(4)));

static __device__ inline unsigned short f2bf(float f) {
    union { float f; unsigned int u; } v; v.f = f;
    unsigned int u = v.u;
    unsigned int r = (u + 0x7FFFu + ((u >> 16) & 1u)) >> 16;   // RNE
    return (unsigned short)r;
}
static __device__ inline float bf2f(unsigned short h) {
    union { unsigned int u; float f; } v; v.u = ((unsigned int)h) << 16;
    return v.f;
}

__global__ __launch_bounds__(256) void k_deg(const int* __restrict__ dst,
                                             int* __restrict__ deg, int E) {
    int e = blockIdx.x * 256 + threadIdx.x;
    if (e < E) atomicAdd(&deg[dst[e]], 1);
}

// ---- 3-kernel scan ---------------------------------------------------------
__global__ __launch_bounds__(256) void k_scan1(const int* __restrict__ deg,
                                               int* __restrict__ escan,
                                               int* __restrict__ bsum, int n) {
    __shared__ int ws4[4];
    int tid = threadIdx.x;
    int base = blockIdx.x * 1024 + tid * 4;
    int d[4];
    #pragma unroll
    for (int j = 0; j < 4; ++j) d[j] = (base + j < n) ? deg[base + j] : 0;
    int s = d[0] + d[1] + d[2] + d[3];
    int lane = tid & 63, wid = tid >> 6;
    int incl = s;
    #pragma unroll
    for (int off = 1; off < 64; off <<= 1) {
        int t = __shfl_up(incl, off, 64);
        if (lane >= off) incl += t;
    }
    if (lane == 63) ws4[wid] = incl;
    __syncthreads();
    int wbase = 0;
    #pragma unroll
    for (int w = 0; w < 4; ++w) if (w < wid) wbase += ws4[w];
    int run = wbase + incl - s;
    #pragma unroll
    for (int j = 0; j < 4; ++j) {
        if (base + j < n) escan[base + j] = run;
        run += d[j];
    }
    if (tid == 255) bsum[blockIdx.x] = run;
}

__global__ __launch_bounds__(1024) void k_scan2(int* __restrict__ bsum, int nb) {
    __shared__ int ws16[16];
    int tid = threadIdx.x;
    int lane = tid & 63, wid = tid >> 6;
    int v = (tid < nb) ? bsum[tid] : 0;
    int incl = v;
    #pragma unroll
    for (int off = 1; off < 64; off <<= 1) {
        int t = __shfl_up(incl, off, 64);
        if (lane >= off) incl += t;
    }
    if (lane == 63) ws16[wid] = incl;
    __syncthreads();
    int wbase = 0;
    for (int w = 0; w < 16; ++w) if (w < wid) wbase += ws16[w];
    if (tid < nb) bsum[tid] = wbase + incl - v;   // exclusive
}

__global__ __launch_bounds__(256) void k_scan3(const int* __restrict__ deg,
                                               const int* __restrict__ escan,
                                               const int* __restrict__ bsum,
                                               int* __restrict__ offs,
                                               int* __restrict__ cursor,
                                               float* __restrict__ invd, int n) {
    int tid = threadIdx.x;
    int base = blockIdx.x * 1024 + tid * 4;
    int bb = bsum[blockIdx.x];
    #pragma unroll
    for (int j = 0; j < 4; ++j) {
        int i = base + j;
        if (i < n) {
            int d = deg[i];
            int off = escan[i] + bb;
            offs[i] = off;
            cursor[i] = off;
            invd[i] = 1.0f / fmaxf((float)d, 1.0f);
            if (i == n - 1) offs[n] = off + d;
        }
    }
}

// ---- x -> bf16 -------------------------------------------------------------
__global__ __launch_bounds__(256) void k_cvt(const float* __restrict__ x,
                                             unsigned short* __restrict__ xb,
                                             int total4) {
    int i = blockIdx.x * 256 + threadIdx.x;
    if (i >= total4) return;
    float4 v = *(const float4*)(x + (size_t)i * 4);
    ushort4 o;
    o.x = f2bf(v.x); o.y = f2bf(v.y); o.z = f2bf(v.z); o.w = f2bf(v.w);
    *(ushort4*)(xb + (size_t)i * 4) = o;
}

// ---- weight pre-swizzle into B-fragment-linear layout ----------------------
// wb[((ks*8+ct)*64+lane)*8 + j] = W[ks*32+(lane>>4)*8+j][ct*16+(lane&15)]
__global__ __launch_bounds__(256) void k_wprep1(const float* __restrict__ Ws,
                                                const float* __restrict__ Wn,
                                                unsigned short* __restrict__ wb) {
    int idx = blockIdx.x * 256 + threadIdx.x;        // 8*8*64*8 = 32768
    if (idx >= 32768) return;
    int j = idx & 7, lane = (idx >> 3) & 63, ct = (idx >> 9) & 7, ks = idx >> 12;
    int k = ks * 32 + ((lane >> 4) & 3) * 8 + j;     // 0..255
    int n = ct * 16 + (lane & 15);                   // 0..127
    float v = (k < 128) ? Ws[k * 128 + n] : Wn[(k - 128) * 128 + n];
    wb[idx] = f2bf(v);
}

__global__ __launch_bounds__(256) void k_wprep2(const float* __restrict__ Ws,
                                                const float* __restrict__ Wn,
                                                unsigned short* __restrict__ wb) {
    int idx = blockIdx.x * 256 + threadIdx.x;        // 4*8*64*8 = 16384
    if (idx >= 16384) return;
    int j = idx & 7, lane = (idx >> 3) & 63, ct = (idx >> 9) & 7, ks = idx >> 12;
    int k = ks * 32 + ((lane >> 4) & 3) * 8 + j;     // 0..127
    int n = ct * 16 + (lane & 15);                   // 0..127; <64 Ws, >=64 Wn
    float v = (n < 64) ? Ws[k * 64 + n] : Wn[k * 64 + (n - 64)];
    wb[idx] = f2bf(v);
}

// ---- XCD-partitioned CSR scatter -------------------------------------------
__global__ __launch_bounds__(256) void k_scatter(const int* __restrict__ src,
                                                 const int* __restrict__ dst,
                                                 int* __restrict__ cursor,
                                                 int* __restrict__ ssrc,
                                                 int E, int P) {
    int part = blockIdx.x & 7;
    int slice = blockIdx.x >> 3;
    int nslices = gridDim.x >> 3;
    int per = (E + nslices - 1) / nslices;
    int beg = slice * per;
    int end = beg + per; if (end > E) end = E;
    int lo = part * P;
    int hi = lo + P;
    for (int e = beg + threadIdx.x; e < end; e += 256) {
        int d = dst[e];
        if (d >= lo && d < hi) {
            int pos = atomicAdd(&cursor[d], 1);
            ssrc[pos] = src[e];
        }
    }
}

// ---- layer-1 aggregation: gather bf16 x rows, mean -> aggb (bf16, N x 128) -
// Edge loop unrolled x4 with two accumulator sets: 4 gathers in flight.
__global__ __launch_bounds__(256) void k_agg1(const unsigned short* __restrict__ xb,
                                              const int* __restrict__ offs,
                                              const int* __restrict__ ssrc,
                                              const float* __restrict__ invd,
                                              unsigned short* __restrict__ aggb,
                                              int n) {
    int node = blockIdx.x * 8 + (threadIdx.x >> 5);
    if (node >= n) return;
    int lane = threadIdx.x & 31;           // 32 lanes x 4 bf16 = 128 feats
    int beg = offs[node], end = offs[node + 1];
    float p0 = 0.f, p1 = 0.f, p2 = 0.f, p3 = 0.f;
    float q0 = 0.f, q1 = 0.f, q2 = 0.f, q3 = 0.f;
    int e = beg;
    for (; e + 4 <= end; e += 4) {
        int s0 = ssrc[e + 0], s1 = ssrc[e + 1];
        int s2 = ssrc[e + 2], s3 = ssrc[e + 3];
        ushort4 v0 = *(const ushort4*)(xb + (size_t)s0 * NFEAT + lane * 4);
        ushort4 v1 = *(const ushort4*)(xb + (size_t)s1 * NFEAT + lane * 4);
        ushort4 v2 = *(const ushort4*)(xb + (size_t)s2 * NFEAT + lane * 4);
        ushort4 v3 = *(const ushort4*)(xb + (size_t)s3 * NFEAT + lane * 4);
        p0 += bf2f(v0.x); p1 += bf2f(v0.y); p2 += bf2f(v0.z); p3 += bf2f(v0.w);
        q0 += bf2f(v1.x); q1 += bf2f(v1.y); q2 += bf2f(v1.z); q3 += bf2f(v1.w);
        p0 += bf2f(v2.x); p1 += bf2f(v2.y); p2 += bf2f(v2.z); p3 += bf2f(v2.w);
        q0 += bf2f(v3.x); q1 += bf2f(v3.y); q2 += bf2f(v3.z); q3 += bf2f(v3.w);
    }
    for (; e < end; ++e) {
        int s = ssrc[e];
        ushort4 v = *(const ushort4*)(xb + (size_t)s * NFEAT + lane * 4);
        p0 += bf2f(v.x); p1 += bf2f(v.y); p2 += bf2f(v.z); p3 += bf2f(v.w);
    }
    float a0 = p0 + q0, a1 = p1 + q1, a2 = p2 + q2, a3 = p3 + q3;
    float iv = invd[node];
    ushort4 o;
    o.x = f2bf(a0 * iv); o.y = f2bf(a1 * iv);
    o.z = f2bf(a2 * iv); o.w = f2bf(a3 * iv);
    *(ushort4*)(aggb + (size_t)node * NFEAT + lane * 4) = o;
}

// ---- layer-1 MFMA GEMM: [xb||aggb] @ Wb1 + b1 -> h1, h1r, h1rb -------------
__global__ __launch_bounds__(256) void k_mm1(const unsigned short* __restrict__ xb,
                                             const unsigned short* __restrict__ aggb,
                                             const unsigned short* __restrict__ wb,
                                             const float* __restrict__ bias,
                                             float* __restrict__ h1,
                                             float* __restrict__ h1r,
                                             unsigned short* __restrict__ h1rb,
                                             int M) {
    int wave = threadIdx.x >> 6, lane = threadIdx.x & 63;
    int rowbase = blockIdx.x * 64 + wave * 16;
    f32x4 acc[8];
    #pragma unroll
    for (int ct = 0; ct < 8; ++ct) acc[ct] = (f32x4){0.f, 0.f, 0.f, 0.f};

    int arow = rowbase + (lane & 15);
    if (arow >= M) arow = M - 1;
    int kq = ((lane >> 4) & 3) * 8;

    #pragma unroll 1
    for (int ks = 0; ks < 8; ++ks) {
        const unsigned short* Ap = (ks < 4) ? xb : aggb;
        bf16x8 a = *(const bf16x8*)(Ap + (size_t)arow * 128 + (ks & 3) * 32 + kq);
        const unsigned short* wp = wb + ((size_t)ks * 8 * 64 + lane) * 8;
        #pragma unroll
        for (int ct = 0; ct < 8; ++ct) {
            bf16x8 b = *(const bf16x8*)(wp + (size_t)ct * 512);
            acc[ct] = __builtin_amdgcn_mfma_f32_16x16x32_bf16(a, b, acc[ct], 0, 0, 0);
        }
    }

    int r0 = rowbase + ((lane >> 4) & 3) * 4;
    int col0 = lane & 15;
    #pragma unroll
    for (int ct = 0; ct < 8; ++ct) {
        int col = ct * 16 + col0;
        float bv = bias[col];
        #pragma unroll
        for (int i = 0; i < 4; ++i) {
            int row = r0 + i;
            if (row < M) {
                float v = acc[ct][i] + bv;
                float vr = fmaxf(v, 0.f);
                size_t o = (size_t)row * 128 + col;
                h1[o] = v;
                h1r[o] = vr;
                h1rb[o] = f2bf(vr);
            }
        }
    }
}

// ---- layer-2 MFMA GEMM: h1rb @ [Ws2|Wn2] -> s2 (f32), p2b (bf16) -----------
__global__ __launch_bounds__(256) void k_mm2(const unsigned short* __restrict__ h1rb,
                                             const unsigned short* __restrict__ wb,
                                             float* __restrict__ s2,
                                             unsigned short* __restrict__ p2b,
                                             int M) {
    int wave = threadIdx.x >> 6, lane = threadIdx.x & 63;
    int rowbase = blockIdx.x * 64 + wave * 16;
    f32x4 acc[8];
    #pragma unroll
    for (int ct = 0; ct < 8; ++ct) acc[ct] = (f32x4){0.f, 0.f, 0.f, 0.f};

    int arow = rowbase + (lane & 15);
    if (arow >= M) arow = M - 1;
    int kq = ((lane >> 4) & 3) * 8;

    #pragma unroll 1
    for (int ks = 0; ks < 4; ++ks) {
        bf16x8 a = *(const bf16x8*)(h1rb + (size_t)arow * 128 + ks * 32 + kq);
        const unsigned short* wp = wb + ((size_t)ks * 8 * 64 + lane) * 8;
        #pragma unroll
        for (int ct = 0; ct < 8; ++ct) {
            bf16x8 b = *(const bf16x8*)(wp + (size_t)ct * 512);
            acc[ct] = __builtin_amdgcn_mfma_f32_16x16x32_bf16(a, b, acc[ct], 0, 0, 0);
        }
    }

    int r0 = rowbase + ((lane >> 4) & 3) * 4;
    int col0 = lane & 15;
    #pragma unroll
    for (int ct = 0; ct < 8; ++ct) {
        int col = ct * 16 + col0;
        #pragma unroll
        for (int i = 0; i < 4; ++i) {
            int row = r0 + i;
            if (row < M) {
                float v = acc[ct][i];
                if (col < 64)
                    s2[(size_t)row * 64 + col] = v;
                else
                    p2b[(size_t)row * 64 + (col - 64)] = f2bf(v);
            }
        }
    }
}

// ---- layer-2 aggregation + epilogue: h2 = s2 + inv*sum(p2b[src]) + b2 ------
// Edge loop unrolled x4 with two accumulator sets: 4 gathers in flight.
__global__ __launch_bounds__(256) void k_agg2(const unsigned short* __restrict__ p2b,
                                              const int* __restrict__ offs,
                                              const int* __restrict__ ssrc,
                                              const float* __restrict__ invd,
                                              const float* __restrict__ s2,
                                              const float* __restrict__ b2,
                                              float* __restrict__ h2a,
                                              float* __restrict__ h2b, int n) {
    int node = blockIdx.x * 16 + (threadIdx.x >> 4);
    if (node >= n) return;
    int lane = threadIdx.x & 15;           // 16 lanes x 4 bf16 = 64 feats
    int beg = offs[node], end = offs[node + 1];
    float p0 = 0.f, p1 = 0.f, p2 = 0.f, p3 = 0.f;
    float q0 = 0.f, q1 = 0.f, q2 = 0.f, q3 = 0.f;
    int e = beg;
    for (; e + 4 <= end; e += 4) {
        int s0 = ssrc[e + 0], s1 = ssrc[e + 1];
        int s2i = ssrc[e + 2], s3 = ssrc[e + 3];
        ushort4 v0 = *(const ushort4*)(p2b + (size_t)s0 * 64 + lane * 4);
        ushort4 v1 = *(const ushort4*)(p2b + (size_t)s1 * 64 + lane * 4);
        ushort4 v2 = *(const ushort4*)(p2b + (size_t)s2i * 64 + lane * 4);
        ushort4 v3 = *(const ushort4*)(p2b + (size_t)s3 * 64 + lane * 4);
        p0 += bf2f(v0.x); p1 += bf2f(v0.y); p2 += bf2f(v0.z); p3 += bf2f(v0.w);
        q0 += bf2f(v1.x); q1 += bf2f(v1.y); q2 += bf2f(v1.z); q3 += bf2f(v1.w);
        p0 += bf2f(v2.x); p1 += bf2f(v2.y); p2 += bf2f(v2.z); p3 += bf2f(v2.w);
        q0 += bf2f(v3.x); q1 += bf2f(v3.y); q2 += bf2f(v3.z); q3 += bf2f(v3.w);
    }
    for (; e < end; ++e) {
        int s = ssrc[e];
        ushort4 v = *(const ushort4*)(p2b + (size_t)s * 64 + lane * 4);
        p0 += bf2f(v.x); p1 += bf2f(v.y); p2 += bf2f(v.z); p3 += bf2f(v.w);
    }
    float a0 = p0 + q0, a1 = p1 + q1, a2 = p2 + q2, a3 = p3 + q3;
    float iv = invd[node];
    float4 sv = *(const float4*)(s2 + (size_t)node * 64 + lane * 4);
    float4 bv = *(const float4*)(b2 + lane * 4);
    float4 r = make_float4(sv.x + a0 * iv + bv.x, sv.y + a1 * iv + bv.y,
                           sv.z + a2 * iv + bv.z, sv.w + a3 * iv + bv.w);
    *(float4*)(h2a + (size_t)node * 64 + lane * 4) = r;
    *(float4*)(h2b + (size_t)node * 64 + lane * 4) = r;
}

static inline size_t align256(size_t x) { return (x + 255) & ~(size_t)255; }

extern "C" void kernel_launch(void* const* d_in, const int* in_sizes, int n_in,
                              void* d_out, int out_size, void* d_ws, size_t ws_size,
                              hipStream_t stream) {
    const float* x   = (const float*)d_in[0];
    const float* Ws1 = (const float*)d_in[1];
    const float* Wn1 = (const float*)d_in[2];
    const float* b1  = (const float*)d_in[3];
    const float* Ws2 = (const float*)d_in[4];
    const float* Wn2 = (const float*)d_in[5];
    const float* b2  = (const float*)d_in[6];
    const int* src   = (const int*)d_in[7];
    const int* dst   = (const int*)d_in[8];

    int E = in_sizes[7];
    int N = in_sizes[0] / NFEAT;

    float* out = (float*)d_out;
    float* h2a = out;                         // h2 (copy 1), N x 64
    float* h1  = out + (size_t)N * 64;        // h1, N x 128
    float* h1r = out + (size_t)N * 192;       // relu(h1), N x 128
    float* h2b = out + (size_t)N * 320;       // h2 (copy 2), N x 64

    char* ws = (char*)d_ws;
    size_t off = 0;
    int*   deg    = (int*)(ws + off);  off = align256(off + (size_t)4 * N);
    int*   offs   = (int*)(ws + off);  off = align256(off + (size_t)4 * (N + 1));
    int*   cursor = (int*)(ws + off);  off = align256(off + (size_t)4 * N);
    float* invd   = (float*)(ws + off); off = align256(off + (size_t)4 * N);
    int*   escan  = (int*)(ws + off);  off = align256(off + (size_t)4 * N);
    int*   bsum   = (int*)(ws + off);  off = align256(off + (size_t)4 * 1024);
    int*   ssrc   = (int*)(ws + off);  off = align256(off + (size_t)4 * E);
    unsigned short* wb1 = (unsigned short*)(ws + off); off = align256(off + 2 * 32768);
    unsigned short* wb2 = (unsigned short*)(ws + off); off = align256(off + 2 * 16384);
    // region1: xb (N*128 bf16 = 25.6 MB) aliases s2 (N*64 f32 = 25.6 MB);
    //          xb dead after k_mm1, s2 written by k_mm2.
    unsigned short* xb = (unsigned short*)(ws + off);
    float*          s2 = (float*)(ws + off);
    off = align256(off + (size_t)N * NFEAT * 2);
    // region2: aggb (N*128 bf16) aliases p2b (N*64 bf16);
    //          aggb dead after k_mm1, p2b written by k_mm2.
    unsigned short* aggb = (unsigned short*)(ws + off);
    unsigned short* p2b  = (unsigned short*)(ws + off);
    off = align256(off + (size_t)N * NFEAT * 2);
    unsigned short* h1rb = (unsigned short*)(ws + off);
    off += (size_t)N * NFEAT * 2;

    int nb = (N + 1023) / 1024;
    int P = (N + 7) / 8;                      // nodes per XCD partition

    hipMemsetAsync(deg, 0, (size_t)4 * N, stream);
    k_deg<<<(E + 255) / 256, 256, 0, stream>>>(dst, deg, E);
    k_scan1<<<nb, 256, 0, stream>>>(deg, escan, bsum, N);
    k_scan2<<<1, 1024, 0, stream>>>(bsum, nb);
    k_scan3<<<nb, 256, 0, stream>>>(deg, escan, bsum, offs, cursor, invd, N);
    k_cvt<<<(N * 32 + 255) / 256, 256, 0, stream>>>(x, xb, N * 32);
    k_wprep1<<<128, 256, 0, stream>>>(Ws1, Wn1, wb1);
    k_wprep2<<<64, 256, 0, stream>>>(Ws2, Wn2, wb2);
    // 8 partitions x 256 slices; slice scanned by all 8 partition-blocks.
    k_scatter<<<8 * 256, 256, 0, stream>>>(src, dst, cursor, ssrc, E, P);

    k_agg1<<<(N + 7) / 8, 256, 0, stream>>>(xb, offs, ssrc, invd, aggb, N);
    k_mm1<<<(N + 63) / 64, 256, 0, stream>>>(xb, aggb, wb1, b1, h1, h1r, h1rb, N);
    k_mm2<<<(N + 63) / 64, 256, 0, stream>>>(h1rb, wb2, s2, p2b, N);
    k_agg2<<<(N + 15) / 16, 256, 0, stream>>>(p2b, offs, ssrc, invd, s2, b2, h2a, h2b, N);
}

// Round 3
// 542.991 us; speedup vs baseline: 1.1890x; 1.0054x over previous
//
#include <hip/hip_runtime.h>
#include <hip/hip_bf16.h>

// ---------------------------------------------------------------------------
// 2-layer GraphSAGE on MI355X. Round 7: partitioned k_deg + MLP-8 agg loops.
//   - Round-6 recap: MLP-4 agg unroll 600->546us; top-5 = harness fills only,
//     so every kernel of ours is <116us. Remaining gap vs ~280us BW model is
//     in atomic/latency-bound kernels.
//   - k_deg was the last kernel doing unpartitioned random atomics (1.6M
//     adds into 400KB from 8 XCDs). Partition it exactly like k_scatter:
//     block (slice,part) scans its edge slice, adds only dst in its node
//     range -> atomics stay in one XCD's L2. (Old scatter's cursor atomics
//     proved this mechanism: they vanished from top-5 after partitioning.)
//   - agg1/agg2 edge loops deepened MLP-4 -> MLP-8 (4 accumulator sets,
//     8 gathers in flight), 4-wide + scalar tails. Pure sum reassociation.
// ---------------------------------------------------------------------------

#define NFEAT 128

typedef __bf16 bf16x8 __attribute__((ext_vector_type(8)));
typedef float  f32x4  __attribute__((ext_vector_type(4)));

static __device__ inline unsigned short f2bf(float f) {
    union { float f; unsigned int u; } v; v.f = f;
    unsigned int u = v.u;
    unsigned int r = (u + 0x7FFFu + ((u >> 16) & 1u)) >> 16;   // RNE
    return (unsigned short)r;
}
static __device__ inline float bf2f(unsigned short h) {
    union { unsigned int u; float f; } v; v.u = ((unsigned int)h) << 16;
    return v.f;
}

// ---- XCD-partitioned degree count ------------------------------------------
// grid = 8 * NSLICE. part=blockIdx&7 owns nodes [part*P, part*P+P); slice
// scans edges [slice*per, ...). All atomics on a given deg line come from one
// XCD -> line stays resident in that L2 instead of ping-ponging across 8.
__global__ __launch_bounds__(256) void k_deg(const int* __restrict__ dst,
                                             int* __restrict__ deg,
                                             int E, int P) {
    int part = blockIdx.x & 7;
    int slice = blockIdx.x >> 3;
    int nslices = gridDim.x >> 3;
    int per = (E + nslices - 1) / nslices;
    int beg = slice * per;
    int end = beg + per; if (end > E) end = E;
    int lo = part * P;
    int hi = lo + P;
    for (int e = beg + threadIdx.x; e < end; e += 256) {
        int d = dst[e];
        if (d >= lo && d < hi) atomicAdd(&deg[d], 1);
    }
}

// ---- 3-kernel scan ---------------------------------------------------------
__global__ __launch_bounds__(256) void k_scan1(const int* __restrict__ deg,
                                               int* __restrict__ escan,
                                               int* __restrict__ bsum, int n) {
    __shared__ int ws4[4];
    int tid = threadIdx.x;
    int base = blockIdx.x * 1024 + tid * 4;
    int d[4];
    #pragma unroll
    for (int j = 0; j < 4; ++j) d[j] = (base + j < n) ? deg[base + j] : 0;
    int s = d[0] + d[1] + d[2] + d[3];
    int lane = tid & 63, wid = tid >> 6;
    int incl = s;
    #pragma unroll
    for (int off = 1; off < 64; off <<= 1) {
        int t = __shfl_up(incl, off, 64);
        if (lane >= off) incl += t;
    }
    if (lane == 63) ws4[wid] = incl;
    __syncthreads();
    int wbase = 0;
    #pragma unroll
    for (int w = 0; w < 4; ++w) if (w < wid) wbase += ws4[w];
    int run = wbase + incl - s;
    #pragma unroll
    for (int j = 0; j < 4; ++j) {
        if (base + j < n) escan[base + j] = run;
        run += d[j];
    }
    if (tid == 255) bsum[blockIdx.x] = run;
}

__global__ __launch_bounds__(1024) void k_scan2(int* __restrict__ bsum, int nb) {
    __shared__ int ws16[16];
    int tid = threadIdx.x;
    int lane = tid & 63, wid = tid >> 6;
    int v = (tid < nb) ? bsum[tid] : 0;
    int incl = v;
    #pragma unroll
    for (int off = 1; off < 64; off <<= 1) {
        int t = __shfl_up(incl, off, 64);
        if (lane >= off) incl += t;
    }
    if (lane == 63) ws16[wid] = incl;
    __syncthreads();
    int wbase = 0;
    for (int w = 0; w < 16; ++w) if (w < wid) wbase += ws16[w];
    if (tid < nb) bsum[tid] = wbase + incl - v;   // exclusive
}

__global__ __launch_bounds__(256) void k_scan3(const int* __restrict__ deg,
                                               const int* __restrict__ escan,
                                               const int* __restrict__ bsum,
                                               int* __restrict__ offs,
                                               int* __restrict__ cursor,
                                               float* __restrict__ invd, int n) {
    int tid = threadIdx.x;
    int base = blockIdx.x * 1024 + tid * 4;
    int bb = bsum[blockIdx.x];
    #pragma unroll
    for (int j = 0; j < 4; ++j) {
        int i = base + j;
        if (i < n) {
            int d = deg[i];
            int off = escan[i] + bb;
            offs[i] = off;
            cursor[i] = off;
            invd[i] = 1.0f / fmaxf((float)d, 1.0f);
            if (i == n - 1) offs[n] = off + d;
        }
    }
}

// ---- x -> bf16 -------------------------------------------------------------
__global__ __launch_bounds__(256) void k_cvt(const float* __restrict__ x,
                                             unsigned short* __restrict__ xb,
                                             int total4) {
    int i = blockIdx.x * 256 + threadIdx.x;
    if (i >= total4) return;
    float4 v = *(const float4*)(x + (size_t)i * 4);
    ushort4 o;
    o.x = f2bf(v.x); o.y = f2bf(v.y); o.z = f2bf(v.z); o.w = f2bf(v.w);
    *(ushort4*)(xb + (size_t)i * 4) = o;
}

// ---- weight pre-swizzle into B-fragment-linear layout ----------------------
// wb[((ks*8+ct)*64+lane)*8 + j] = W[ks*32+(lane>>4)*8+j][ct*16+(lane&15)]
__global__ __launch_bounds__(256) void k_wprep1(const float* __restrict__ Ws,
                                                const float* __restrict__ Wn,
                                                unsigned short* __restrict__ wb) {
    int idx = blockIdx.x * 256 + threadIdx.x;        // 8*8*64*8 = 32768
    if (idx >= 32768) return;
    int j = idx & 7, lane = (idx >> 3) & 63, ct = (idx >> 9) & 7, ks = idx >> 12;
    int k = ks * 32 + ((lane >> 4) & 3) * 8 + j;     // 0..255
    int n = ct * 16 + (lane & 15);                   // 0..127
    float v = (k < 128) ? Ws[k * 128 + n] : Wn[(k - 128) * 128 + n];
    wb[idx] = f2bf(v);
}

__global__ __launch_bounds__(256) void k_wprep2(const float* __restrict__ Ws,
                                                const float* __restrict__ Wn,
                                                unsigned short* __restrict__ wb) {
    int idx = blockIdx.x * 256 + threadIdx.x;        // 4*8*64*8 = 16384
    if (idx >= 16384) return;
    int j = idx & 7, lane = (idx >> 3) & 63, ct = (idx >> 9) & 7, ks = idx >> 12;
    int k = ks * 32 + ((lane >> 4) & 3) * 8 + j;     // 0..127
    int n = ct * 16 + (lane & 15);                   // 0..127; <64 Ws, >=64 Wn
    float v = (n < 64) ? Ws[k * 64 + n] : Wn[k * 64 + (n - 64)];
    wb[idx] = f2bf(v);
}

// ---- XCD-partitioned CSR scatter -------------------------------------------
__global__ __launch_bounds__(256) void k_scatter(const int* __restrict__ src,
                                                 const int* __restrict__ dst,
                                                 int* __restrict__ cursor,
                                                 int* __restrict__ ssrc,
                                                 int E, int P) {
    int part = blockIdx.x & 7;
    int slice = blockIdx.x >> 3;
    int nslices = gridDim.x >> 3;
    int per = (E + nslices - 1) / nslices;
    int beg = slice * per;
    int end = beg + per; if (end > E) end = E;
    int lo = part * P;
    int hi = lo + P;
    for (int e = beg + threadIdx.x; e < end; e += 256) {
        int d = dst[e];
        if (d >= lo && d < hi) {
            int pos = atomicAdd(&cursor[d], 1);
            ssrc[pos] = src[e];
        }
    }
}

// ---- layer-1 aggregation: gather bf16 x rows, mean -> aggb (bf16, N x 128) -
// Edge loop MLP-8: 8 gathers in flight, 4 independent accumulator sets.
__global__ __launch_bounds__(256) void k_agg1(const unsigned short* __restrict__ xb,
                                              const int* __restrict__ offs,
                                              const int* __restrict__ ssrc,
                                              const float* __restrict__ invd,
                                              unsigned short* __restrict__ aggb,
                                              int n) {
    int node = blockIdx.x * 8 + (threadIdx.x >> 5);
    if (node >= n) return;
    int lane = threadIdx.x & 31;           // 32 lanes x 4 bf16 = 128 feats
    int beg = offs[node], end = offs[node + 1];
    float p0 = 0.f, p1 = 0.f, p2 = 0.f, p3 = 0.f;
    float q0 = 0.f, q1 = 0.f, q2 = 0.f, q3 = 0.f;
    float r0 = 0.f, r1 = 0.f, r2 = 0.f, r3 = 0.f;
    float t0 = 0.f, t1 = 0.f, t2 = 0.f, t3 = 0.f;
    int e = beg;
    for (; e + 8 <= end; e += 8) {
        int s0 = ssrc[e + 0], s1 = ssrc[e + 1], s2 = ssrc[e + 2], s3 = ssrc[e + 3];
        int s4 = ssrc[e + 4], s5 = ssrc[e + 5], s6 = ssrc[e + 6], s7 = ssrc[e + 7];
        ushort4 v0 = *(const ushort4*)(xb + (size_t)s0 * NFEAT + lane * 4);
        ushort4 v1 = *(const ushort4*)(xb + (size_t)s1 * NFEAT + lane * 4);
        ushort4 v2 = *(const ushort4*)(xb + (size_t)s2 * NFEAT + lane * 4);
        ushort4 v3 = *(const ushort4*)(xb + (size_t)s3 * NFEAT + lane * 4);
        ushort4 v4 = *(const ushort4*)(xb + (size_t)s4 * NFEAT + lane * 4);
        ushort4 v5 = *(const ushort4*)(xb + (size_t)s5 * NFEAT + lane * 4);
        ushort4 v6 = *(const ushort4*)(xb + (size_t)s6 * NFEAT + lane * 4);
        ushort4 v7 = *(const ushort4*)(xb + (size_t)s7 * NFEAT + lane * 4);
        p0 += bf2f(v0.x); p1 += bf2f(v0.y); p2 += bf2f(v0.z); p3 += bf2f(v0.w);
        q0 += bf2f(v1.x); q1 += bf2f(v1.y); q2 += bf2f(v1.z); q3 += bf2f(v1.w);
        r0 += bf2f(v2.x); r1 += bf2f(v2.y); r2 += bf2f(v2.z); r3 += bf2f(v2.w);
        t0 += bf2f(v3.x); t1 += bf2f(v3.y); t2 += bf2f(v3.z); t3 += bf2f(v3.w);
        p0 += bf2f(v4.x); p1 += bf2f(v4.y); p2 += bf2f(v4.z); p3 += bf2f(v4.w);
        q0 += bf2f(v5.x); q1 += bf2f(v5.y); q2 += bf2f(v5.z); q3 += bf2f(v5.w);
        r0 += bf2f(v6.x); r1 += bf2f(v6.y); r2 += bf2f(v6.z); r3 += bf2f(v6.w);
        t0 += bf2f(v7.x); t1 += bf2f(v7.y); t2 += bf2f(v7.z); t3 += bf2f(v7.w);
    }
    for (; e + 4 <= end; e += 4) {
        int s0 = ssrc[e + 0], s1 = ssrc[e + 1], s2 = ssrc[e + 2], s3 = ssrc[e + 3];
        ushort4 v0 = *(const ushort4*)(xb + (size_t)s0 * NFEAT + lane * 4);
        ushort4 v1 = *(const ushort4*)(xb + (size_t)s1 * NFEAT + lane * 4);
        ushort4 v2 = *(const ushort4*)(xb + (size_t)s2 * NFEAT + lane * 4);
        ushort4 v3 = *(const ushort4*)(xb + (size_t)s3 * NFEAT + lane * 4);
        p0 += bf2f(v0.x); p1 += bf2f(v0.y); p2 += bf2f(v0.z); p3 += bf2f(v0.w);
        q0 += bf2f(v1.x); q1 += bf2f(v1.y); q2 += bf2f(v1.z); q3 += bf2f(v1.w);
        r0 += bf2f(v2.x); r1 += bf2f(v2.y); r2 += bf2f(v2.z); r3 += bf2f(v2.w);
        t0 += bf2f(v3.x); t1 += bf2f(v3.y); t2 += bf2f(v3.z); t3 += bf2f(v3.w);
    }
    for (; e < end; ++e) {
        int s = ssrc[e];
        ushort4 v = *(const ushort4*)(xb + (size_t)s * NFEAT + lane * 4);
        p0 += bf2f(v.x); p1 += bf2f(v.y); p2 += bf2f(v.z); p3 += bf2f(v.w);
    }
    float a0 = (p0 + q0) + (r0 + t0);
    float a1 = (p1 + q1) + (r1 + t1);
    float a2 = (p2 + q2) + (r2 + t2);
    float a3 = (p3 + q3) + (r3 + t3);
    float iv = invd[node];
    ushort4 o;
    o.x = f2bf(a0 * iv); o.y = f2bf(a1 * iv);
    o.z = f2bf(a2 * iv); o.w = f2bf(a3 * iv);
    *(ushort4*)(aggb + (size_t)node * NFEAT + lane * 4) = o;
}

// ---- layer-1 MFMA GEMM: [xb||aggb] @ Wb1 + b1 -> h1, h1r, h1rb -------------
__global__ __launch_bounds__(256) void k_mm1(const unsigned short* __restrict__ xb,
                                             const unsigned short* __restrict__ aggb,
                                             const unsigned short* __restrict__ wb,
                                             const float* __restrict__ bias,
                                             float* __restrict__ h1,
                                             float* __restrict__ h1r,
                                             unsigned short* __restrict__ h1rb,
                                             int M) {
    int wave = threadIdx.x >> 6, lane = threadIdx.x & 63;
    int rowbase = blockIdx.x * 64 + wave * 16;
    f32x4 acc[8];
    #pragma unroll
    for (int ct = 0; ct < 8; ++ct) acc[ct] = (f32x4){0.f, 0.f, 0.f, 0.f};

    int arow = rowbase + (lane & 15);
    if (arow >= M) arow = M - 1;
    int kq = ((lane >> 4) & 3) * 8;

    #pragma unroll 1
    for (int ks = 0; ks < 8; ++ks) {
        const unsigned short* Ap = (ks < 4) ? xb : aggb;
        bf16x8 a = *(const bf16x8*)(Ap + (size_t)arow * 128 + (ks & 3) * 32 + kq);
        const unsigned short* wp = wb + ((size_t)ks * 8 * 64 + lane) * 8;
        #pragma unroll
        for (int ct = 0; ct < 8; ++ct) {
            bf16x8 b = *(const bf16x8*)(wp + (size_t)ct * 512);
            acc[ct] = __builtin_amdgcn_mfma_f32_16x16x32_bf16(a, b, acc[ct], 0, 0, 0);
        }
    }

    int r0 = rowbase + ((lane >> 4) & 3) * 4;
    int col0 = lane & 15;
    #pragma unroll
    for (int ct = 0; ct < 8; ++ct) {
        int col = ct * 16 + col0;
        float bv = bias[col];
        #pragma unroll
        for (int i = 0; i < 4; ++i) {
            int row = r0 + i;
            if (row < M) {
                float v = acc[ct][i] + bv;
                float vr = fmaxf(v, 0.f);
                size_t o = (size_t)row * 128 + col;
                h1[o] = v;
                h1r[o] = vr;
                h1rb[o] = f2bf(vr);
            }
        }
    }
}

// ---- layer-2 MFMA GEMM: h1rb @ [Ws2|Wn2] -> s2 (f32), p2b (bf16) -----------
__global__ __launch_bounds__(256) void k_mm2(const unsigned short* __restrict__ h1rb,
                                             const unsigned short* __restrict__ wb,
                                             float* __restrict__ s2,
                                             unsigned short* __restrict__ p2b,
                                             int M) {
    int wave = threadIdx.x >> 6, lane = threadIdx.x & 63;
    int rowbase = blockIdx.x * 64 + wave * 16;
    f32x4 acc[8];
    #pragma unroll
    for (int ct = 0; ct < 8; ++ct) acc[ct] = (f32x4){0.f, 0.f, 0.f, 0.f};

    int arow = rowbase + (lane & 15);
    if (arow >= M) arow = M - 1;
    int kq = ((lane >> 4) & 3) * 8;

    #pragma unroll 1
    for (int ks = 0; ks < 4; ++ks) {
        bf16x8 a = *(const bf16x8*)(h1rb + (size_t)arow * 128 + ks * 32 + kq);
        const unsigned short* wp = wb + ((size_t)ks * 8 * 64 + lane) * 8;
        #pragma unroll
        for (int ct = 0; ct < 8; ++ct) {
            bf16x8 b = *(const bf16x8*)(wp + (size_t)ct * 512);
            acc[ct] = __builtin_amdgcn_mfma_f32_16x16x32_bf16(a, b, acc[ct], 0, 0, 0);
        }
    }

    int r0 = rowbase + ((lane >> 4) & 3) * 4;
    int col0 = lane & 15;
    #pragma unroll
    for (int ct = 0; ct < 8; ++ct) {
        int col = ct * 16 + col0;
        #pragma unroll
        for (int i = 0; i < 4; ++i) {
            int row = r0 + i;
            if (row < M) {
                float v = acc[ct][i];
                if (col < 64)
                    s2[(size_t)row * 64 + col] = v;
                else
                    p2b[(size_t)row * 64 + (col - 64)] = f2bf(v);
            }
        }
    }
}

// ---- layer-2 aggregation + epilogue: h2 = s2 + inv*sum(p2b[src]) + b2 ------
// Edge loop MLP-8: 8 gathers in flight, 4 independent accumulator sets.
__global__ __launch_bounds__(256) void k_agg2(const unsigned short* __restrict__ p2b,
                                              const int* __restrict__ offs,
                                              const int* __restrict__ ssrc,
                                              const float* __restrict__ invd,
                                              const float* __restrict__ s2,
                                              const float* __restrict__ b2,
                                              float* __restrict__ h2a,
                                              float* __restrict__ h2b, int n) {
    int node = blockIdx.x * 16 + (threadIdx.x >> 4);
    if (node >= n) return;
    int lane = threadIdx.x & 15;           // 16 lanes x 4 bf16 = 64 feats
    int beg = offs[node], end = offs[node + 1];
    float p0 = 0.f, p1 = 0.f, p2 = 0.f, p3 = 0.f;
    float q0 = 0.f, q1 = 0.f, q2 = 0.f, q3 = 0.f;
    float r0 = 0.f, r1 = 0.f, r2 = 0.f, r3 = 0.f;
    float t0 = 0.f, t1 = 0.f, t2 = 0.f, t3 = 0.f;
    int e = beg;
    for (; e + 8 <= end; e += 8) {
        int s0 = ssrc[e + 0], s1 = ssrc[e + 1], s2i = ssrc[e + 2], s3 = ssrc[e + 3];
        int s4 = ssrc[e + 4], s5 = ssrc[e + 5], s6 = ssrc[e + 6], s7 = ssrc[e + 7];
        ushort4 v0 = *(const ushort4*)(p2b + (size_t)s0 * 64 + lane * 4);
        ushort4 v1 = *(const ushort4*)(p2b + (size_t)s1 * 64 + lane * 4);
        ushort4 v2 = *(const ushort4*)(p2b + (size_t)s2i * 64 + lane * 4);
        ushort4 v3 = *(const ushort4*)(p2b + (size_t)s3 * 64 + lane * 4);
        ushort4 v4 = *(const ushort4*)(p2b + (size_t)s4 * 64 + lane * 4);
        ushort4 v5 = *(const ushort4*)(p2b + (size_t)s5 * 64 + lane * 4);
        ushort4 v6 = *(const ushort4*)(p2b + (size_t)s6 * 64 + lane * 4);
        ushort4 v7 = *(const ushort4*)(p2b + (size_t)s7 * 64 + lane * 4);
        p0 += bf2f(v0.x); p1 += bf2f(v0.y); p2 += bf2f(v0.z); p3 += bf2f(v0.w);
        q0 += bf2f(v1.x); q1 += bf2f(v1.y); q2 += bf2f(v1.z); q3 += bf2f(v1.w);
        r0 += bf2f(v2.x); r1 += bf2f(v2.y); r2 += bf2f(v2.z); r3 += bf2f(v2.w);
        t0 += bf2f(v3.x); t1 += bf2f(v3.y); t2 += bf2f(v3.z); t3 += bf2f(v3.w);
        p0 += bf2f(v4.x); p1 += bf2f(v4.y); p2 += bf2f(v4.z); p3 += bf2f(v4.w);
        q0 += bf2f(v5.x); q1 += bf2f(v5.y); q2 += bf2f(v5.z); q3 += bf2f(v5.w);
        r0 += bf2f(v6.x); r1 += bf2f(v6.y); r2 += bf2f(v6.z); r3 += bf2f(v6.w);
        t0 += bf2f(v7.x); t1 += bf2f(v7.y); t2 += bf2f(v7.z); t3 += bf2f(v7.w);
    }
    for (; e + 4 <= end; e += 4) {
        int s0 = ssrc[e + 0], s1 = ssrc[e + 1], s2i = ssrc[e + 2], s3 = ssrc[e + 3];
        ushort4 v0 = *(const ushort4*)(p2b + (size_t)s0 * 64 + lane * 4);
        ushort4 v1 = *(const ushort4*)(p2b + (size_t)s1 * 64 + lane * 4);
        ushort4 v2 = *(const ushort4*)(p2b + (size_t)s2i * 64 + lane * 4);
        ushort4 v3 = *(const ushort4*)(p2b + (size_t)s3 * 64 + lane * 4);
        p0 += bf2f(v0.x); p1 += bf2f(v0.y); p2 += bf2f(v0.z); p3 += bf2f(v0.w);
        q0 += bf2f(v1.x); q1 += bf2f(v1.y); q2 += bf2f(v1.z); q3 += bf2f(v1.w);
        r0 += bf2f(v2.x); r1 += bf2f(v2.y); r2 += bf2f(v2.z); r3 += bf2f(v2.w);
        t0 += bf2f(v3.x); t1 += bf2f(v3.y); t2 += bf2f(v3.z); t3 += bf2f(v3.w);
    }
    for (; e < end; ++e) {
        int s = ssrc[e];
        ushort4 v = *(const ushort4*)(p2b + (size_t)s * 64 + lane * 4);
        p0 += bf2f(v.x); p1 += bf2f(v.y); p2 += bf2f(v.z); p3 += bf2f(v.w);
    }
    float a0 = (p0 + q0) + (r0 + t0);
    float a1 = (p1 + q1) + (r1 + t1);
    float a2 = (p2 + q2) + (r2 + t2);
    float a3 = (p3 + q3) + (r3 + t3);
    float iv = invd[node];
    float4 sv = *(const float4*)(s2 + (size_t)node * 64 + lane * 4);
    float4 bv = *(const float4*)(b2 + lane * 4);
    float4 r = make_float4(sv.x + a0 * iv + bv.x, sv.y + a1 * iv + bv.y,
                           sv.z + a2 * iv + bv.z, sv.w + a3 * iv + bv.w);
    *(float4*)(h2a + (size_t)node * 64 + lane * 4) = r;
    *(float4*)(h2b + (size_t)node * 64 + lane * 4) = r;
}

static inline size_t align256(size_t x) { return (x + 255) & ~(size_t)255; }

extern "C" void kernel_launch(void* const* d_in, const int* in_sizes, int n_in,
                              void* d_out, int out_size, void* d_ws, size_t ws_size,
                              hipStream_t stream) {
    const float* x   = (const float*)d_in[0];
    const float* Ws1 = (const float*)d_in[1];
    const float* Wn1 = (const float*)d_in[2];
    const float* b1  = (const float*)d_in[3];
    const float* Ws2 = (const float*)d_in[4];
    const float* Wn2 = (const float*)d_in[5];
    const float* b2  = (const float*)d_in[6];
    const int* src   = (const int*)d_in[7];
    const int* dst   = (const int*)d_in[8];

    int E = in_sizes[7];
    int N = in_sizes[0] / NFEAT;

    float* out = (float*)d_out;
    float* h2a = out;                         // h2 (copy 1), N x 64
    float* h1  = out + (size_t)N * 64;        // h1, N x 128
    float* h1r = out + (size_t)N * 192;       // relu(h1), N x 128
    float* h2b = out + (size_t)N * 320;       // h2 (copy 2), N x 64

    char* ws = (char*)d_ws;
    size_t off = 0;
    int*   deg    = (int*)(ws + off);  off = align256(off + (size_t)4 * N);
    int*   offs   = (int*)(ws + off);  off = align256(off + (size_t)4 * (N + 1));
    int*   cursor = (int*)(ws + off);  off = align256(off + (size_t)4 * N);
    float* invd   = (float*)(ws + off); off = align256(off + (size_t)4 * N);
    int*   escan  = (int*)(ws + off);  off = align256(off + (size_t)4 * N);
    int*   bsum   = (int*)(ws + off);  off = align256(off + (size_t)4 * 1024);
    int*   ssrc   = (int*)(ws + off);  off = align256(off + (size_t)4 * E);
    unsigned short* wb1 = (unsigned short*)(ws + off); off = align256(off + 2 * 32768);
    unsigned short* wb2 = (unsigned short*)(ws + off); off = align256(off + 2 * 16384);
    // region1: xb (N*128 bf16 = 25.6 MB) aliases s2 (N*64 f32 = 25.6 MB);
    //          xb dead after k_mm1, s2 written by k_mm2.
    unsigned short* xb = (unsigned short*)(ws + off);
    float*          s2 = (float*)(ws + off);
    off = align256(off + (size_t)N * NFEAT * 2);
    // region2: aggb (N*128 bf16) aliases p2b (N*64 bf16);
    //          aggb dead after k_mm1, p2b written by k_mm2.
    unsigned short* aggb = (unsigned short*)(ws + off);
    unsigned short* p2b  = (unsigned short*)(ws + off);
    off = align256(off + (size_t)N * NFEAT * 2);
    unsigned short* h1rb = (unsigned short*)(ws + off);
    off += (size_t)N * NFEAT * 2;

    int nb = (N + 1023) / 1024;
    int P = (N + 7) / 8;                      // nodes per XCD partition

    hipMemsetAsync(deg, 0, (size_t)4 * N, stream);
    k_deg<<<8 * 256, 256, 0, stream>>>(dst, deg, E, P);
    k_scan1<<<nb, 256, 0, stream>>>(deg, escan, bsum, N);
    k_scan2<<<1, 1024, 0, stream>>>(bsum, nb);
    k_scan3<<<nb, 256, 0, stream>>>(deg, escan, bsum, offs, cursor, invd, N);
    k_cvt<<<(N * 32 + 255) / 256, 256, 0, stream>>>(x, xb, N * 32);
    k_wprep1<<<128, 256, 0, stream>>>(Ws1, Wn1, wb1);
    k_wprep2<<<64, 256, 0, stream>>>(Ws2, Wn2, wb2);
    // 8 partitions x 256 slices; slice scanned by all 8 partition-blocks.
    k_scatter<<<8 * 256, 256, 0, stream>>>(src, dst, cursor, ssrc, E, P);

    k_agg1<<<(N + 7) / 8, 256, 0, stream>>>(xb, offs, ssrc, invd, aggb, N);
    k_mm1<<<(N + 63) / 64, 256, 0, stream>>>(xb, aggb, wb1, b1, h1, h1r, h1rb, N);
    k_mm2<<<(N + 63) / 64, 256, 0, stream>>>(h1rb, wb2, s2, p2b, N);
    k_agg2<<<(N + 15) / 16, 256, 0, stream>>>(p2b, offs, ssrc, invd, s2, b2, h2a, h2b, N);
}

// Round 5
// 515.879 us; speedup vs baseline: 1.2515x; 1.0526x over previous
//
#include <hip/hip_runtime.h>
#include <hip/hip_bf16.h>

// ---------------------------------------------------------------------------
// 2-layer GraphSAGE on MI355X. Round 8b: (compile fix) fuse agg1 into mm1;
// NT output stores.
//   - Round-7 recap: partitioned k_deg + MLP-8 were neutral (543us) ->
//     latency levers exhausted; remaining cost is traffic/structure.
//   - k_mm1f: gather-mean now computed IN k_mm1's registers. Each node owned
//     by 4 lanes (lane = m + 16q); lane accumulates the 32 feats its MFMA
//     A-fragment needs (feat = 32j + q*8 + jj). Mean -> bf16 -> feeds MFMA
//     ks=4..7 directly. Kills aggb (51.2 MB round-trip), one dispatch, no LDS.
//   - h1/h1r/h2a/h2b are write-once outputs -> __builtin_nontemporal_store
//     (keep xb/p2b/h1rb gather tables hot in L2/L3). NT stores go through
//     Clang ext-vector f32x4 (HIP_vector_type float4* is rejected by the
//     builtin).
//   - k_prep merges k_cvt + k_wprep1 + k_wprep2 (13 -> 10 dispatches).
// ---------------------------------------------------------------------------

#define NFEAT 128

typedef __bf16 bf16x8 __attribute__((ext_vector_type(8)));
typedef float  f32x4  __attribute__((ext_vector_type(4)));
typedef unsigned short ushort8v __attribute__((ext_vector_type(8)));

static __device__ inline unsigned short f2bf(float f) {
    union { float f; unsigned int u; } v; v.f = f;
    unsigned int u = v.u;
    unsigned int r = (u + 0x7FFFu + ((u >> 16) & 1u)) >> 16;   // RNE
    return (unsigned short)r;
}
static __device__ inline float bf2f(unsigned short h) {
    union { unsigned int u; float f; } v; v.u = ((unsigned int)h) << 16;
    return v.f;
}

// ---- XCD-partitioned degree count ------------------------------------------
__global__ __launch_bounds__(256) void k_deg(const int* __restrict__ dst,
                                             int* __restrict__ deg,
                                             int E, int P) {
    int part = blockIdx.x & 7;
    int slice = blockIdx.x >> 3;
    int nslices = gridDim.x >> 3;
    int per = (E + nslices - 1) / nslices;
    int beg = slice * per;
    int end = beg + per; if (end > E) end = E;
    int lo = part * P;
    int hi = lo + P;
    for (int e = beg + threadIdx.x; e < end; e += 256) {
        int d = dst[e];
        if (d >= lo && d < hi) atomicAdd(&deg[d], 1);
    }
}

// ---- 3-kernel scan ---------------------------------------------------------
__global__ __launch_bounds__(256) void k_scan1(const int* __restrict__ deg,
                                               int* __restrict__ escan,
                                               int* __restrict__ bsum, int n) {
    __shared__ int ws4[4];
    int tid = threadIdx.x;
    int base = blockIdx.x * 1024 + tid * 4;
    int d[4];
    #pragma unroll
    for (int j = 0; j < 4; ++j) d[j] = (base + j < n) ? deg[base + j] : 0;
    int s = d[0] + d[1] + d[2] + d[3];
    int lane = tid & 63, wid = tid >> 6;
    int incl = s;
    #pragma unroll
    for (int off = 1; off < 64; off <<= 1) {
        int t = __shfl_up(incl, off, 64);
        if (lane >= off) incl += t;
    }
    if (lane == 63) ws4[wid] = incl;
    __syncthreads();
    int wbase = 0;
    #pragma unroll
    for (int w = 0; w < 4; ++w) if (w < wid) wbase += ws4[w];
    int run = wbase + incl - s;
    #pragma unroll
    for (int j = 0; j < 4; ++j) {
        if (base + j < n) escan[base + j] = run;
        run += d[j];
    }
    if (tid == 255) bsum[blockIdx.x] = run;
}

__global__ __launch_bounds__(1024) void k_scan2(int* __restrict__ bsum, int nb) {
    __shared__ int ws16[16];
    int tid = threadIdx.x;
    int lane = tid & 63, wid = tid >> 6;
    int v = (tid < nb) ? bsum[tid] : 0;
    int incl = v;
    #pragma unroll
    for (int off = 1; off < 64; off <<= 1) {
        int t = __shfl_up(incl, off, 64);
        if (lane >= off) incl += t;
    }
    if (lane == 63) ws16[wid] = incl;
    __syncthreads();
    int wbase = 0;
    for (int w = 0; w < 16; ++w) if (w < wid) wbase += ws16[w];
    if (tid < nb) bsum[tid] = wbase + incl - v;   // exclusive
}

__global__ __launch_bounds__(256) void k_scan3(const int* __restrict__ deg,
                                               const int* __restrict__ escan,
                                               const int* __restrict__ bsum,
                                               int* __restrict__ offs,
                                               int* __restrict__ cursor,
                                               float* __restrict__ invd, int n) {
    int tid = threadIdx.x;
    int base = blockIdx.x * 1024 + tid * 4;
    int bb = bsum[blockIdx.x];
    #pragma unroll
    for (int j = 0; j < 4; ++j) {
        int i = base + j;
        if (i < n) {
            int d = deg[i];
            int off = escan[i] + bb;
            offs[i] = off;
            cursor[i] = off;
            invd[i] = 1.0f / fmaxf((float)d, 1.0f);
            if (i == n - 1) offs[n] = off + d;
        }
    }
}

// ---- merged prep: x->bf16 cvt, weight pre-swizzle (both layers) ------------
// blocks [0,C): cvt; [C,C+128): wprep1; [C+128,C+192): wprep2.
__global__ __launch_bounds__(256) void k_prep(const float* __restrict__ x,
                                              unsigned short* __restrict__ xb,
                                              const float* __restrict__ Ws1,
                                              const float* __restrict__ Wn1,
                                              unsigned short* __restrict__ wb1,
                                              const float* __restrict__ Ws2,
                                              const float* __restrict__ Wn2,
                                              unsigned short* __restrict__ wb2,
                                              int total4, int C) {
    int b = blockIdx.x;
    if (b < C) {
        int i = b * 256 + threadIdx.x;
        if (i >= total4) return;
        float4 v = *(const float4*)(x + (size_t)i * 4);
        ushort4 o;
        o.x = f2bf(v.x); o.y = f2bf(v.y); o.z = f2bf(v.z); o.w = f2bf(v.w);
        *(ushort4*)(xb + (size_t)i * 4) = o;
    } else if (b < C + 128) {
        int idx = (b - C) * 256 + threadIdx.x;        // 8*8*64*8 = 32768
        int j = idx & 7, lane = (idx >> 3) & 63, ct = (idx >> 9) & 7, ks = idx >> 12;
        int k = ks * 32 + ((lane >> 4) & 3) * 8 + j;  // 0..255
        int n = ct * 16 + (lane & 15);                // 0..127
        float v = (k < 128) ? Ws1[k * 128 + n] : Wn1[(k - 128) * 128 + n];
        wb1[idx] = f2bf(v);
    } else {
        int idx = (b - C - 128) * 256 + threadIdx.x;  // 4*8*64*8 = 16384
        int j = idx & 7, lane = (idx >> 3) & 63, ct = (idx >> 9) & 7, ks = idx >> 12;
        int k = ks * 32 + ((lane >> 4) & 3) * 8 + j;  // 0..127
        int n = ct * 16 + (lane & 15);                // 0..127; <64 Ws, >=64 Wn
        float v = (n < 64) ? Ws2[k * 64 + n] : Wn2[k * 64 + (n - 64)];
        wb2[idx] = f2bf(v);
    }
}

// ---- XCD-partitioned CSR scatter -------------------------------------------
__global__ __launch_bounds__(256) void k_scatter(const int* __restrict__ src,
                                                 const int* __restrict__ dst,
                                                 int* __restrict__ cursor,
                                                 int* __restrict__ ssrc,
                                                 int E, int P) {
    int part = blockIdx.x & 7;
    int slice = blockIdx.x >> 3;
    int nslices = gridDim.x >> 3;
    int per = (E + nslices - 1) / nslices;
    int beg = slice * per;
    int end = beg + per; if (end > E) end = E;
    int lo = part * P;
    int hi = lo + P;
    for (int e = beg + threadIdx.x; e < end; e += 256) {
        int d = dst[e];
        if (d >= lo && d < hi) {
            int pos = atomicAdd(&cursor[d], 1);
            ssrc[pos] = src[e];
        }
    }
}

// ---- fused layer-1: gather-mean (registers) + MFMA GEMM --------------------
// Wave owns 16 nodes; node m handled by lanes m+16q (q=0..3). Lane gathers
// feats {32j + q*8 + jj : j=0..3, jj=0..7} = exactly its A-fragment slots for
// the agg half (ks=4..7). xb half (ks=0..3) loads from global as before.
__global__ __launch_bounds__(256) void k_mm1f(const unsigned short* __restrict__ xb,
                                              const int* __restrict__ offs,
                                              const int* __restrict__ ssrc,
                                              const float* __restrict__ invd,
                                              const unsigned short* __restrict__ wb,
                                              const float* __restrict__ bias,
                                              float* __restrict__ h1,
                                              float* __restrict__ h1r,
                                              unsigned short* __restrict__ h1rb,
                                              int M) {
    int wave = threadIdx.x >> 6, lane = threadIdx.x & 63;
    int rowbase = blockIdx.x * 64 + wave * 16;
    int node = rowbase + (lane & 15);
    if (node >= M) node = M - 1;
    int q = (lane >> 4) & 3;
    int kq = q * 8;

    // ---- gather-mean: 32 feats/lane in f32 ----
    float a0[8], a1[8], a2[8], a3[8];
    #pragma unroll
    for (int jj = 0; jj < 8; ++jj) { a0[jj]=0.f; a1[jj]=0.f; a2[jj]=0.f; a3[jj]=0.f; }
    int beg = offs[node], end = offs[node + 1];
    int e = beg;
    for (; e + 2 <= end; e += 2) {
        int s0 = ssrc[e], s1 = ssrc[e + 1];
        const unsigned short* r0p = xb + (size_t)s0 * NFEAT + kq;
        const unsigned short* r1p = xb + (size_t)s1 * NFEAT + kq;
        ushort8v u0 = *(const ushort8v*)(r0p);
        ushort8v u1 = *(const ushort8v*)(r0p + 32);
        ushort8v u2 = *(const ushort8v*)(r0p + 64);
        ushort8v u3 = *(const ushort8v*)(r0p + 96);
        ushort8v w0 = *(const ushort8v*)(r1p);
        ushort8v w1 = *(const ushort8v*)(r1p + 32);
        ushort8v w2 = *(const ushort8v*)(r1p + 64);
        ushort8v w3 = *(const ushort8v*)(r1p + 96);
        #pragma unroll
        for (int jj = 0; jj < 8; ++jj) {
            a0[jj] += bf2f(u0[jj]) + bf2f(w0[jj]);
            a1[jj] += bf2f(u1[jj]) + bf2f(w1[jj]);
            a2[jj] += bf2f(u2[jj]) + bf2f(w2[jj]);
            a3[jj] += bf2f(u3[jj]) + bf2f(w3[jj]);
        }
    }
    if (e < end) {
        int s0 = ssrc[e];
        const unsigned short* rp = xb + (size_t)s0 * NFEAT + kq;
        ushort8v u0 = *(const ushort8v*)(rp);
        ushort8v u1 = *(const ushort8v*)(rp + 32);
        ushort8v u2 = *(const ushort8v*)(rp + 64);
        ushort8v u3 = *(const ushort8v*)(rp + 96);
        #pragma unroll
        for (int jj = 0; jj < 8; ++jj) {
            a0[jj] += bf2f(u0[jj]);
            a1[jj] += bf2f(u1[jj]);
            a2[jj] += bf2f(u2[jj]);
            a3[jj] += bf2f(u3[jj]);
        }
    }
    float iv = invd[node];
    ushort8v g0, g1, g2, g3;
    #pragma unroll
    for (int jj = 0; jj < 8; ++jj) {
        g0[jj] = f2bf(a0[jj] * iv); g1[jj] = f2bf(a1[jj] * iv);
        g2[jj] = f2bf(a2[jj] * iv); g3[jj] = f2bf(a3[jj] * iv);
    }
    bf16x8 ag0 = *(bf16x8*)&g0;
    bf16x8 ag1 = *(bf16x8*)&g1;
    bf16x8 ag2 = *(bf16x8*)&g2;
    bf16x8 ag3 = *(bf16x8*)&g3;

    // ---- MFMA: ks 0..3 from xb (global), ks 4..7 from registers ----
    f32x4 acc[8];
    #pragma unroll
    for (int ct = 0; ct < 8; ++ct) acc[ct] = (f32x4){0.f, 0.f, 0.f, 0.f};

    #pragma unroll 1
    for (int ks = 0; ks < 4; ++ks) {
        bf16x8 a = *(const bf16x8*)(xb + (size_t)node * NFEAT + ks * 32 + kq);
        const unsigned short* wp = wb + ((size_t)ks * 512 + lane) * 8;
        #pragma unroll
        for (int ct = 0; ct < 8; ++ct) {
            bf16x8 b = *(const bf16x8*)(wp + (size_t)ct * 512);
            acc[ct] = __builtin_amdgcn_mfma_f32_16x16x32_bf16(a, b, acc[ct], 0, 0, 0);
        }
    }
    {
        const unsigned short* wl = wb + (size_t)lane * 8;
        #pragma unroll
        for (int ct = 0; ct < 8; ++ct)
            acc[ct] = __builtin_amdgcn_mfma_f32_16x16x32_bf16(
                ag0, *(const bf16x8*)(wl + (size_t)4 * 4096 + ct * 512), acc[ct], 0, 0, 0);
        #pragma unroll
        for (int ct = 0; ct < 8; ++ct)
            acc[ct] = __builtin_amdgcn_mfma_f32_16x16x32_bf16(
                ag1, *(const bf16x8*)(wl + (size_t)5 * 4096 + ct * 512), acc[ct], 0, 0, 0);
        #pragma unroll
        for (int ct = 0; ct < 8; ++ct)
            acc[ct] = __builtin_amdgcn_mfma_f32_16x16x32_bf16(
                ag2, *(const bf16x8*)(wl + (size_t)6 * 4096 + ct * 512), acc[ct], 0, 0, 0);
        #pragma unroll
        for (int ct = 0; ct < 8; ++ct)
            acc[ct] = __builtin_amdgcn_mfma_f32_16x16x32_bf16(
                ag3, *(const bf16x8*)(wl + (size_t)7 * 4096 + ct * 512), acc[ct], 0, 0, 0);
    }

    int r0 = rowbase + q * 4;
    int col0 = lane & 15;
    #pragma unroll
    for (int ct = 0; ct < 8; ++ct) {
        int col = ct * 16 + col0;
        float bv = bias[col];
        #pragma unroll
        for (int i = 0; i < 4; ++i) {
            int row = r0 + i;
            if (row < M) {
                float v = acc[ct][i] + bv;
                float vr = fmaxf(v, 0.f);
                size_t o = (size_t)row * 128 + col;
                __builtin_nontemporal_store(v, &h1[o]);
                __builtin_nontemporal_store(vr, &h1r[o]);
                h1rb[o] = f2bf(vr);
            }
        }
    }
}

// ---- layer-2 MFMA GEMM: h1rb @ [Ws2|Wn2] -> s2 (f32), p2b (bf16) -----------
__global__ __launch_bounds__(256) void k_mm2(const unsigned short* __restrict__ h1rb,
                                             const unsigned short* __restrict__ wb,
                                             float* __restrict__ s2,
                                             unsigned short* __restrict__ p2b,
                                             int M) {
    int wave = threadIdx.x >> 6, lane = threadIdx.x & 63;
    int rowbase = blockIdx.x * 64 + wave * 16;
    f32x4 acc[8];
    #pragma unroll
    for (int ct = 0; ct < 8; ++ct) acc[ct] = (f32x4){0.f, 0.f, 0.f, 0.f};

    int arow = rowbase + (lane & 15);
    if (arow >= M) arow = M - 1;
    int kq = ((lane >> 4) & 3) * 8;

    #pragma unroll 1
    for (int ks = 0; ks < 4; ++ks) {
        bf16x8 a = *(const bf16x8*)(h1rb + (size_t)arow * 128 + ks * 32 + kq);
        const unsigned short* wp = wb + ((size_t)ks * 512 + lane) * 8;
        #pragma unroll
        for (int ct = 0; ct < 8; ++ct) {
            bf16x8 b = *(const bf16x8*)(wp + (size_t)ct * 512);
            acc[ct] = __builtin_amdgcn_mfma_f32_16x16x32_bf16(a, b, acc[ct], 0, 0, 0);
        }
    }

    int r0 = rowbase + ((lane >> 4) & 3) * 4;
    int col0 = lane & 15;
    #pragma unroll
    for (int ct = 0; ct < 8; ++ct) {
        int col = ct * 16 + col0;
        #pragma unroll
        for (int i = 0; i < 4; ++i) {
            int row = r0 + i;
            if (row < M) {
                float v = acc[ct][i];
                if (col < 64)
                    s2[(size_t)row * 64 + col] = v;
                else
                    p2b[(size_t)row * 64 + (col - 64)] = f2bf(v);
            }
        }
    }
}

// ---- layer-2 aggregation + epilogue: h2 = s2 + inv*sum(p2b[src]) + b2 ------
__global__ __launch_bounds__(256) void k_agg2(const unsigned short* __restrict__ p2b,
                                              const int* __restrict__ offs,
                                              const int* __restrict__ ssrc,
                                              const float* __restrict__ invd,
                                              const float* __restrict__ s2,
                                              const float* __restrict__ b2,
                                              float* __restrict__ h2a,
                                              float* __restrict__ h2b, int n) {
    int node = blockIdx.x * 16 + (threadIdx.x >> 4);
    if (node >= n) return;
    int lane = threadIdx.x & 15;           // 16 lanes x 4 bf16 = 64 feats
    int beg = offs[node], end = offs[node + 1];
    float p0 = 0.f, p1 = 0.f, p2 = 0.f, p3 = 0.f;
    float q0 = 0.f, q1 = 0.f, q2 = 0.f, q3 = 0.f;
    float r0 = 0.f, r1 = 0.f, r2 = 0.f, r3 = 0.f;
    float t0 = 0.f, t1 = 0.f, t2 = 0.f, t3 = 0.f;
    int e = beg;
    for (; e + 8 <= end; e += 8) {
        int s0 = ssrc[e + 0], s1 = ssrc[e + 1], s2i = ssrc[e + 2], s3 = ssrc[e + 3];
        int s4 = ssrc[e + 4], s5 = ssrc[e + 5], s6 = ssrc[e + 6], s7 = ssrc[e + 7];
        ushort4 v0 = *(const ushort4*)(p2b + (size_t)s0 * 64 + lane * 4);
        ushort4 v1 = *(const ushort4*)(p2b + (size_t)s1 * 64 + lane * 4);
        ushort4 v2 = *(const ushort4*)(p2b + (size_t)s2i * 64 + lane * 4);
        ushort4 v3 = *(const ushort4*)(p2b + (size_t)s3 * 64 + lane * 4);
        ushort4 v4 = *(const ushort4*)(p2b + (size_t)s4 * 64 + lane * 4);
        ushort4 v5 = *(const ushort4*)(p2b + (size_t)s5 * 64 + lane * 4);
        ushort4 v6 = *(const ushort4*)(p2b + (size_t)s6 * 64 + lane * 4);
        ushort4 v7 = *(const ushort4*)(p2b + (size_t)s7 * 64 + lane * 4);
        p0 += bf2f(v0.x); p1 += bf2f(v0.y); p2 += bf2f(v0.z); p3 += bf2f(v0.w);
        q0 += bf2f(v1.x); q1 += bf2f(v1.y); q2 += bf2f(v1.z); q3 += bf2f(v1.w);
        r0 += bf2f(v2.x); r1 += bf2f(v2.y); r2 += bf2f(v2.z); r3 += bf2f(v2.w);
        t0 += bf2f(v3.x); t1 += bf2f(v3.y); t2 += bf2f(v3.z); t3 += bf2f(v3.w);
        p0 += bf2f(v4.x); p1 += bf2f(v4.y); p2 += bf2f(v4.z); p3 += bf2f(v4.w);
        q0 += bf2f(v5.x); q1 += bf2f(v5.y); q2 += bf2f(v5.z); q3 += bf2f(v5.w);
        r0 += bf2f(v6.x); r1 += bf2f(v6.y); r2 += bf2f(v6.z); r3 += bf2f(v6.w);
        t0 += bf2f(v7.x); t1 += bf2f(v7.y); t2 += bf2f(v7.z); t3 += bf2f(v7.w);
    }
    for (; e + 4 <= end; e += 4) {
        int s0 = ssrc[e + 0], s1 = ssrc[e + 1], s2i = ssrc[e + 2], s3 = ssrc[e + 3];
        ushort4 v0 = *(const ushort4*)(p2b + (size_t)s0 * 64 + lane * 4);
        ushort4 v1 = *(const ushort4*)(p2b + (size_t)s1 * 64 + lane * 4);
        ushort4 v2 = *(const ushort4*)(p2b + (size_t)s2i * 64 + lane * 4);
        ushort4 v3 = *(const ushort4*)(p2b + (size_t)s3 * 64 + lane * 4);
        p0 += bf2f(v0.x); p1 += bf2f(v0.y); p2 += bf2f(v0.z); p3 += bf2f(v0.w);
        q0 += bf2f(v1.x); q1 += bf2f(v1.y); q2 += bf2f(v1.z); q3 += bf2f(v1.w);
        r0 += bf2f(v2.x); r1 += bf2f(v2.y); r2 += bf2f(v2.z); r3 += bf2f(v2.w);
        t0 += bf2f(v3.x); t1 += bf2f(v3.y); t2 += bf2f(v3.z); t3 += bf2f(v3.w);
    }
    for (; e < end; ++e) {
        int s = ssrc[e];
        ushort4 v = *(const ushort4*)(p2b + (size_t)s * 64 + lane * 4);
        p0 += bf2f(v.x); p1 += bf2f(v.y); p2 += bf2f(v.z); p3 += bf2f(v.w);
    }
    float a0 = (p0 + q0) + (r0 + t0);
    float a1 = (p1 + q1) + (r1 + t1);
    float a2 = (p2 + q2) + (r2 + t2);
    float a3 = (p3 + q3) + (r3 + t3);
    float iv = invd[node];
    float4 sv = *(const float4*)(s2 + (size_t)node * 64 + lane * 4);
    float4 bv = *(const float4*)(b2 + lane * 4);
    f32x4 r;
    r[0] = sv.x + a0 * iv + bv.x;
    r[1] = sv.y + a1 * iv + bv.y;
    r[2] = sv.z + a2 * iv + bv.z;
    r[3] = sv.w + a3 * iv + bv.w;
    __builtin_nontemporal_store(r, (f32x4*)(h2a + (size_t)node * 64 + lane * 4));
    __builtin_nontemporal_store(r, (f32x4*)(h2b + (size_t)node * 64 + lane * 4));
}

static inline size_t align256(size_t x) { return (x + 255) & ~(size_t)255; }

extern "C" void kernel_launch(void* const* d_in, const int* in_sizes, int n_in,
                              void* d_out, int out_size, void* d_ws, size_t ws_size,
                              hipStream_t stream) {
    const float* x   = (const float*)d_in[0];
    const float* Ws1 = (const float*)d_in[1];
    const float* Wn1 = (const float*)d_in[2];
    const float* b1  = (const float*)d_in[3];
    const float* Ws2 = (const float*)d_in[4];
    const float* Wn2 = (const float*)d_in[5];
    const float* b2  = (const float*)d_in[6];
    const int* src   = (const int*)d_in[7];
    const int* dst   = (const int*)d_in[8];

    int E = in_sizes[7];
    int N = in_sizes[0] / NFEAT;

    float* out = (float*)d_out;
    float* h2a = out;                         // h2 (copy 1), N x 64
    float* h1  = out + (size_t)N * 64;        // h1, N x 128
    float* h1r = out + (size_t)N * 192;       // relu(h1), N x 128
    float* h2b = out + (size_t)N * 320;       // h2 (copy 2), N x 64

    char* ws = (char*)d_ws;
    size_t off = 0;
    int*   deg    = (int*)(ws + off);  off = align256(off + (size_t)4 * N);
    int*   offs   = (int*)(ws + off);  off = align256(off + (size_t)4 * (N + 1));
    int*   cursor = (int*)(ws + off);  off = align256(off + (size_t)4 * N);
    float* invd   = (float*)(ws + off); off = align256(off + (size_t)4 * N);
    int*   escan  = (int*)(ws + off);  off = align256(off + (size_t)4 * N);
    int*   bsum   = (int*)(ws + off);  off = align256(off + (size_t)4 * 1024);
    int*   ssrc   = (int*)(ws + off);  off = align256(off + (size_t)4 * E);
    unsigned short* wb1 = (unsigned short*)(ws + off); off = align256(off + 2 * 32768);
    unsigned short* wb2 = (unsigned short*)(ws + off); off = align256(off + 2 * 16384);
    // region1: xb (N*128 bf16 = 25.6 MB) aliases s2 (N*64 f32 = 25.6 MB);
    //          xb dead after k_mm1f, s2 written by k_mm2.
    unsigned short* xb = (unsigned short*)(ws + off);
    float*          s2 = (float*)(ws + off);
    off = align256(off + (size_t)N * NFEAT * 2);
    unsigned short* p2b = (unsigned short*)(ws + off);
    off = align256(off + (size_t)N * 64 * 2);
    unsigned short* h1rb = (unsigned short*)(ws + off);
    off += (size_t)N * NFEAT * 2;

    int nb = (N + 1023) / 1024;
    int P = (N + 7) / 8;                      // nodes per XCD partition
    int C = (N * 32 + 255) / 256;             // cvt blocks in k_prep

    hipMemsetAsync(deg, 0, (size_t)4 * N, stream);
    k_deg<<<8 * 256, 256, 0, stream>>>(dst, deg, E, P);
    k_scan1<<<nb, 256, 0, stream>>>(deg, escan, bsum, N);
    k_scan2<<<1, 1024, 0, stream>>>(bsum, nb);
    k_scan3<<<nb, 256, 0, stream>>>(deg, escan, bsum, offs, cursor, invd, N);
    k_prep<<<C + 192, 256, 0, stream>>>(x, xb, Ws1, Wn1, wb1, Ws2, Wn2, wb2,
                                        N * 32, C);
    k_scatter<<<8 * 256, 256, 0, stream>>>(src, dst, cursor, ssrc, E, P);

    k_mm1f<<<(N + 63) / 64, 256, 0, stream>>>(xb, offs, ssrc, invd, wb1, b1,
                                              h1, h1r, h1rb, N);
    k_mm2<<<(N + 63) / 64, 256, 0, stream>>>(h1rb, wb2, s2, p2b, N);
    k_agg2<<<(N + 15) / 16, 256, 0, stream>>>(p2b, offs, ssrc, invd, s2, b2, h2a, h2b, N);
}

// Round 6
// 504.295 us; speedup vs baseline: 1.2803x; 1.0230x over previous
//
#include <hip/hip_runtime.h>
#include <hip/hip_bf16.h>

// ---------------------------------------------------------------------------
// 2-layer GraphSAGE on MI355X. Round 9: fuse mm2 into mm1f (kill h1rb).
//   - Round-8 recap: k_mm1f surfaced at 136us (FETCH 191MB, 2.4TB/s random
//     gather, VALU 14%, Mfma 2%) -> between latency- and random-line-BW-bound.
//   - k_mmf: each block already computes the FULL 64x128 h1r tile. Stage it
//     in LDS (16KB, XOR-swizzled per G4's D=128 conflict rule), barrier, run
//     mm2's K=128 MFMA from LDS, write s2/p2b directly. Kills the 51.2MB
//     h1rb round-trip and one dispatch; mm2 compute hides under occupancy.
//   - s2 un-aliased from xb (fusion would race: phase-1 reads xb while other
//     blocks' phase-2 writes s2). h1rb freed -> net workspace unchanged.
// ---------------------------------------------------------------------------

#define NFEAT 128

typedef __bf16 bf16x8 __attribute__((ext_vector_type(8)));
typedef float  f32x4  __attribute__((ext_vector_type(4)));
typedef unsigned short ushort8v __attribute__((ext_vector_type(8)));

static __device__ inline unsigned short f2bf(float f) {
    union { float f; unsigned int u; } v; v.f = f;
    unsigned int u = v.u;
    unsigned int r = (u + 0x7FFFu + ((u >> 16) & 1u)) >> 16;   // RNE
    return (unsigned short)r;
}
static __device__ inline float bf2f(unsigned short h) {
    union { unsigned int u; float f; } v; v.u = ((unsigned int)h) << 16;
    return v.f;
}

// ---- XCD-partitioned degree count ------------------------------------------
__global__ __launch_bounds__(256) void k_deg(const int* __restrict__ dst,
                                             int* __restrict__ deg,
                                             int E, int P) {
    int part = blockIdx.x & 7;
    int slice = blockIdx.x >> 3;
    int nslices = gridDim.x >> 3;
    int per = (E + nslices - 1) / nslices;
    int beg = slice * per;
    int end = beg + per; if (end > E) end = E;
    int lo = part * P;
    int hi = lo + P;
    for (int e = beg + threadIdx.x; e < end; e += 256) {
        int d = dst[e];
        if (d >= lo && d < hi) atomicAdd(&deg[d], 1);
    }
}

// ---- 3-kernel scan ---------------------------------------------------------
__global__ __launch_bounds__(256) void k_scan1(const int* __restrict__ deg,
                                               int* __restrict__ escan,
                                               int* __restrict__ bsum, int n) {
    __shared__ int ws4[4];
    int tid = threadIdx.x;
    int base = blockIdx.x * 1024 + tid * 4;
    int d[4];
    #pragma unroll
    for (int j = 0; j < 4; ++j) d[j] = (base + j < n) ? deg[base + j] : 0;
    int s = d[0] + d[1] + d[2] + d[3];
    int lane = tid & 63, wid = tid >> 6;
    int incl = s;
    #pragma unroll
    for (int off = 1; off < 64; off <<= 1) {
        int t = __shfl_up(incl, off, 64);
        if (lane >= off) incl += t;
    }
    if (lane == 63) ws4[wid] = incl;
    __syncthreads();
    int wbase = 0;
    #pragma unroll
    for (int w = 0; w < 4; ++w) if (w < wid) wbase += ws4[w];
    int run = wbase + incl - s;
    #pragma unroll
    for (int j = 0; j < 4; ++j) {
        if (base + j < n) escan[base + j] = run;
        run += d[j];
    }
    if (tid == 255) bsum[blockIdx.x] = run;
}

__global__ __launch_bounds__(1024) void k_scan2(int* __restrict__ bsum, int nb) {
    __shared__ int ws16[16];
    int tid = threadIdx.x;
    int lane = tid & 63, wid = tid >> 6;
    int v = (tid < nb) ? bsum[tid] : 0;
    int incl = v;
    #pragma unroll
    for (int off = 1; off < 64; off <<= 1) {
        int t = __shfl_up(incl, off, 64);
        if (lane >= off) incl += t;
    }
    if (lane == 63) ws16[wid] = incl;
    __syncthreads();
    int wbase = 0;
    for (int w = 0; w < 16; ++w) if (w < wid) wbase += ws16[w];
    if (tid < nb) bsum[tid] = wbase + incl - v;   // exclusive
}

__global__ __launch_bounds__(256) void k_scan3(const int* __restrict__ deg,
                                               const int* __restrict__ escan,
                                               const int* __restrict__ bsum,
                                               int* __restrict__ offs,
                                               int* __restrict__ cursor,
                                               float* __restrict__ invd, int n) {
    int tid = threadIdx.x;
    int base = blockIdx.x * 1024 + tid * 4;
    int bb = bsum[blockIdx.x];
    #pragma unroll
    for (int j = 0; j < 4; ++j) {
        int i = base + j;
        if (i < n) {
            int d = deg[i];
            int off = escan[i] + bb;
            offs[i] = off;
            cursor[i] = off;
            invd[i] = 1.0f / fmaxf((float)d, 1.0f);
            if (i == n - 1) offs[n] = off + d;
        }
    }
}

// ---- merged prep: x->bf16 cvt, weight pre-swizzle (both layers) ------------
__global__ __launch_bounds__(256) void k_prep(const float* __restrict__ x,
                                              unsigned short* __restrict__ xb,
                                              const float* __restrict__ Ws1,
                                              const float* __restrict__ Wn1,
                                              unsigned short* __restrict__ wb1,
                                              const float* __restrict__ Ws2,
                                              const float* __restrict__ Wn2,
                                              unsigned short* __restrict__ wb2,
                                              int total4, int C) {
    int b = blockIdx.x;
    if (b < C) {
        int i = b * 256 + threadIdx.x;
        if (i >= total4) return;
        float4 v = *(const float4*)(x + (size_t)i * 4);
        ushort4 o;
        o.x = f2bf(v.x); o.y = f2bf(v.y); o.z = f2bf(v.z); o.w = f2bf(v.w);
        *(ushort4*)(xb + (size_t)i * 4) = o;
    } else if (b < C + 128) {
        int idx = (b - C) * 256 + threadIdx.x;        // 8*8*64*8 = 32768
        int j = idx & 7, lane = (idx >> 3) & 63, ct = (idx >> 9) & 7, ks = idx >> 12;
        int k = ks * 32 + ((lane >> 4) & 3) * 8 + j;  // 0..255
        int n = ct * 16 + (lane & 15);                // 0..127
        float v = (k < 128) ? Ws1[k * 128 + n] : Wn1[(k - 128) * 128 + n];
        wb1[idx] = f2bf(v);
    } else {
        int idx = (b - C - 128) * 256 + threadIdx.x;  // 4*8*64*8 = 16384
        int j = idx & 7, lane = (idx >> 3) & 63, ct = (idx >> 9) & 7, ks = idx >> 12;
        int k = ks * 32 + ((lane >> 4) & 3) * 8 + j;  // 0..127
        int n = ct * 16 + (lane & 15);                // 0..127; <64 Ws, >=64 Wn
        float v = (n < 64) ? Ws2[k * 64 + n] : Wn2[k * 64 + (n - 64)];
        wb2[idx] = f2bf(v);
    }
}

// ---- XCD-partitioned CSR scatter -------------------------------------------
__global__ __launch_bounds__(256) void k_scatter(const int* __restrict__ src,
                                                 const int* __restrict__ dst,
                                                 int* __restrict__ cursor,
                                                 int* __restrict__ ssrc,
                                                 int E, int P) {
    int part = blockIdx.x & 7;
    int slice = blockIdx.x >> 3;
    int nslices = gridDim.x >> 3;
    int per = (E + nslices - 1) / nslices;
    int beg = slice * per;
    int end = beg + per; if (end > E) end = E;
    int lo = part * P;
    int hi = lo + P;
    for (int e = beg + threadIdx.x; e < end; e += 256) {
        int d = dst[e];
        if (d >= lo && d < hi) {
            int pos = atomicAdd(&cursor[d], 1);
            ssrc[pos] = src[e];
        }
    }
}

// ---- fused layer-1 + layer-2 GEMM ------------------------------------------
// Phase 1 (= round-8 k_mm1f): gather-mean in registers + MFMA -> h1/h1r tile
// (64 rows x 128 cols) in acc. Epilogue stores h1/h1r (NT) and stages
// bf16(h1r) into XOR-swizzled LDS.
// Phase 2 (= old k_mm2): A-frags from LDS, K=128 MFMA vs wb2 -> s2, p2b.
__global__ __launch_bounds__(256) void k_mmf(const unsigned short* __restrict__ xb,
                                             const int* __restrict__ offs,
                                             const int* __restrict__ ssrc,
                                             const float* __restrict__ invd,
                                             const unsigned short* __restrict__ wb,
                                             const float* __restrict__ bias,
                                             const unsigned short* __restrict__ wb2,
                                             float* __restrict__ h1,
                                             float* __restrict__ h1r,
                                             float* __restrict__ s2,
                                             unsigned short* __restrict__ p2b,
                                             int M) {
    __shared__ unsigned short lh[64 * 128];   // 16 KB, XOR-swizzled rows
    int wave = threadIdx.x >> 6, lane = threadIdx.x & 63;
    int rowbase = blockIdx.x * 64 + wave * 16;
    int node = rowbase + (lane & 15);
    if (node >= M) node = M - 1;
    int q = (lane >> 4) & 3;
    int kq = q * 8;

    // ---- gather-mean: 32 feats/lane in f32 ----
    float a0[8], a1[8], a2[8], a3[8];
    #pragma unroll
    for (int jj = 0; jj < 8; ++jj) { a0[jj]=0.f; a1[jj]=0.f; a2[jj]=0.f; a3[jj]=0.f; }
    int beg = offs[node], end = offs[node + 1];
    int e = beg;
    for (; e + 2 <= end; e += 2) {
        int s0 = ssrc[e], s1 = ssrc[e + 1];
        const unsigned short* r0p = xb + (size_t)s0 * NFEAT + kq;
        const unsigned short* r1p = xb + (size_t)s1 * NFEAT + kq;
        ushort8v u0 = *(const ushort8v*)(r0p);
        ushort8v u1 = *(const ushort8v*)(r0p + 32);
        ushort8v u2 = *(const ushort8v*)(r0p + 64);
        ushort8v u3 = *(const ushort8v*)(r0p + 96);
        ushort8v w0 = *(const ushort8v*)(r1p);
        ushort8v w1 = *(const ushort8v*)(r1p + 32);
        ushort8v w2 = *(const ushort8v*)(r1p + 64);
        ushort8v w3 = *(const ushort8v*)(r1p + 96);
        #pragma unroll
        for (int jj = 0; jj < 8; ++jj) {
            a0[jj] += bf2f(u0[jj]) + bf2f(w0[jj]);
            a1[jj] += bf2f(u1[jj]) + bf2f(w1[jj]);
            a2[jj] += bf2f(u2[jj]) + bf2f(w2[jj]);
            a3[jj] += bf2f(u3[jj]) + bf2f(w3[jj]);
        }
    }
    if (e < end) {
        int s0 = ssrc[e];
        const unsigned short* rp = xb + (size_t)s0 * NFEAT + kq;
        ushort8v u0 = *(const ushort8v*)(rp);
        ushort8v u1 = *(const ushort8v*)(rp + 32);
        ushort8v u2 = *(const ushort8v*)(rp + 64);
        ushort8v u3 = *(const ushort8v*)(rp + 96);
        #pragma unroll
        for (int jj = 0; jj < 8; ++jj) {
            a0[jj] += bf2f(u0[jj]);
            a1[jj] += bf2f(u1[jj]);
            a2[jj] += bf2f(u2[jj]);
            a3[jj] += bf2f(u3[jj]);
        }
    }
    float iv = invd[node];
    ushort8v g0, g1, g2, g3;
    #pragma unroll
    for (int jj = 0; jj < 8; ++jj) {
        g0[jj] = f2bf(a0[jj] * iv); g1[jj] = f2bf(a1[jj] * iv);
        g2[jj] = f2bf(a2[jj] * iv); g3[jj] = f2bf(a3[jj] * iv);
    }
    bf16x8 ag0 = *(bf16x8*)&g0;
    bf16x8 ag1 = *(bf16x8*)&g1;
    bf16x8 ag2 = *(bf16x8*)&g2;
    bf16x8 ag3 = *(bf16x8*)&g3;

    // ---- MFMA layer 1: ks 0..3 from xb, ks 4..7 from registers ----
    f32x4 acc[8];
    #pragma unroll
    for (int ct = 0; ct < 8; ++ct) acc[ct] = (f32x4){0.f, 0.f, 0.f, 0.f};

    #pragma unroll 1
    for (int ks = 0; ks < 4; ++ks) {
        bf16x8 a = *(const bf16x8*)(xb + (size_t)node * NFEAT + ks * 32 + kq);
        const unsigned short* wp = wb + ((size_t)ks * 512 + lane) * 8;
        #pragma unroll
        for (int ct = 0; ct < 8; ++ct) {
            bf16x8 b = *(const bf16x8*)(wp + (size_t)ct * 512);
            acc[ct] = __builtin_amdgcn_mfma_f32_16x16x32_bf16(a, b, acc[ct], 0, 0, 0);
        }
    }
    {
        const unsigned short* wl = wb + (size_t)lane * 8;
        #pragma unroll
        for (int ct = 0; ct < 8; ++ct)
            acc[ct] = __builtin_amdgcn_mfma_f32_16x16x32_bf16(
                ag0, *(const bf16x8*)(wl + (size_t)4 * 4096 + ct * 512), acc[ct], 0, 0, 0);
        #pragma unroll
        for (int ct = 0; ct < 8; ++ct)
            acc[ct] = __builtin_amdgcn_mfma_f32_16x16x32_bf16(
                ag1, *(const bf16x8*)(wl + (size_t)5 * 4096 + ct * 512), acc[ct], 0, 0, 0);
        #pragma unroll
        for (int ct = 0; ct < 8; ++ct)
            acc[ct] = __builtin_amdgcn_mfma_f32_16x16x32_bf16(
                ag2, *(const bf16x8*)(wl + (size_t)6 * 4096 + ct * 512), acc[ct], 0, 0, 0);
        #pragma unroll
        for (int ct = 0; ct < 8; ++ct)
            acc[ct] = __builtin_amdgcn_mfma_f32_16x16x32_bf16(
                ag3, *(const bf16x8*)(wl + (size_t)7 * 4096 + ct * 512), acc[ct], 0, 0, 0);
    }

    // ---- epilogue 1: h1/h1r global (NT), bf16(h1r) -> swizzled LDS ----
    int r0 = rowbase + q * 4;
    int lr0 = wave * 16 + q * 4;              // local row base
    int col0 = lane & 15;
    #pragma unroll
    for (int ct = 0; ct < 8; ++ct) {
        int col = ct * 16 + col0;
        float bv = bias[col];
        #pragma unroll
        for (int i = 0; i < 4; ++i) {
            int row = r0 + i;
            float v = acc[ct][i] + bv;
            float vr = fmaxf(v, 0.f);
            int lr = lr0 + i;
            lh[(lr * 128 + col) ^ ((lr & 7) << 3)] = f2bf(vr);
            if (row < M) {
                size_t o = (size_t)row * 128 + col;
                __builtin_nontemporal_store(v, &h1[o]);
                __builtin_nontemporal_store(vr, &h1r[o]);
            }
        }
    }
    __syncthreads();

    // ---- phase 2 (old k_mm2): A from LDS, K=128 vs wb2 -> s2 | p2b ----
    f32x4 acc2[8];
    #pragma unroll
    for (int ct = 0; ct < 8; ++ct) acc2[ct] = (f32x4){0.f, 0.f, 0.f, 0.f};
    int lr = wave * 16 + (lane & 15);
    #pragma unroll 1
    for (int ks = 0; ks < 4; ++ks) {
        int ui = (lr * 128 + ks * 32 + kq) ^ ((lr & 7) << 3);
        bf16x8 a = *(const bf16x8*)&lh[ui];
        const unsigned short* wp = wb2 + ((size_t)ks * 512 + lane) * 8;
        #pragma unroll
        for (int ct = 0; ct < 8; ++ct) {
            bf16x8 b = *(const bf16x8*)(wp + (size_t)ct * 512);
            acc2[ct] = __builtin_amdgcn_mfma_f32_16x16x32_bf16(a, b, acc2[ct], 0, 0, 0);
        }
    }
    #pragma unroll
    for (int ct = 0; ct < 8; ++ct) {
        int col = ct * 16 + col0;
        #pragma unroll
        for (int i = 0; i < 4; ++i) {
            int row = r0 + i;
            if (row < M) {
                float v = acc2[ct][i];
                if (col < 64)
                    s2[(size_t)row * 64 + col] = v;
                else
                    p2b[(size_t)row * 64 + (col - 64)] = f2bf(v);
            }
        }
    }
}

// ---- layer-2 aggregation + epilogue: h2 = s2 + inv*sum(p2b[src]) + b2 ------
__global__ __launch_bounds__(256) void k_agg2(const unsigned short* __restrict__ p2b,
                                              const int* __restrict__ offs,
                                              const int* __restrict__ ssrc,
                                              const float* __restrict__ invd,
                                              const float* __restrict__ s2,
                                              const float* __restrict__ b2,
                                              float* __restrict__ h2a,
                                              float* __restrict__ h2b, int n) {
    int node = blockIdx.x * 16 + (threadIdx.x >> 4);
    if (node >= n) return;
    int lane = threadIdx.x & 15;           // 16 lanes x 4 bf16 = 64 feats
    int beg = offs[node], end = offs[node + 1];
    float p0 = 0.f, p1 = 0.f, p2 = 0.f, p3 = 0.f;
    float q0 = 0.f, q1 = 0.f, q2 = 0.f, q3 = 0.f;
    float r0 = 0.f, r1 = 0.f, r2 = 0.f, r3 = 0.f;
    float t0 = 0.f, t1 = 0.f, t2 = 0.f, t3 = 0.f;
    int e = beg;
    for (; e + 8 <= end; e += 8) {
        int s0 = ssrc[e + 0], s1 = ssrc[e + 1], s2i = ssrc[e + 2], s3 = ssrc[e + 3];
        int s4 = ssrc[e + 4], s5 = ssrc[e + 5], s6 = ssrc[e + 6], s7 = ssrc[e + 7];
        ushort4 v0 = *(const ushort4*)(p2b + (size_t)s0 * 64 + lane * 4);
        ushort4 v1 = *(const ushort4*)(p2b + (size_t)s1 * 64 + lane * 4);
        ushort4 v2 = *(const ushort4*)(p2b + (size_t)s2i * 64 + lane * 4);
        ushort4 v3 = *(const ushort4*)(p2b + (size_t)s3 * 64 + lane * 4);
        ushort4 v4 = *(const ushort4*)(p2b + (size_t)s4 * 64 + lane * 4);
        ushort4 v5 = *(const ushort4*)(p2b + (size_t)s5 * 64 + lane * 4);
        ushort4 v6 = *(const ushort4*)(p2b + (size_t)s6 * 64 + lane * 4);
        ushort4 v7 = *(const ushort4*)(p2b + (size_t)s7 * 64 + lane * 4);
        p0 += bf2f(v0.x); p1 += bf2f(v0.y); p2 += bf2f(v0.z); p3 += bf2f(v0.w);
        q0 += bf2f(v1.x); q1 += bf2f(v1.y); q2 += bf2f(v1.z); q3 += bf2f(v1.w);
        r0 += bf2f(v2.x); r1 += bf2f(v2.y); r2 += bf2f(v2.z); r3 += bf2f(v2.w);
        t0 += bf2f(v3.x); t1 += bf2f(v3.y); t2 += bf2f(v3.z); t3 += bf2f(v3.w);
        p0 += bf2f(v4.x); p1 += bf2f(v4.y); p2 += bf2f(v4.z); p3 += bf2f(v4.w);
        q0 += bf2f(v5.x); q1 += bf2f(v5.y); q2 += bf2f(v5.z); q3 += bf2f(v5.w);
        r0 += bf2f(v6.x); r1 += bf2f(v6.y); r2 += bf2f(v6.z); r3 += bf2f(v6.w);
        t0 += bf2f(v7.x); t1 += bf2f(v7.y); t2 += bf2f(v7.z); t3 += bf2f(v7.w);
    }
    for (; e + 4 <= end; e += 4) {
        int s0 = ssrc[e + 0], s1 = ssrc[e + 1], s2i = ssrc[e + 2], s3 = ssrc[e + 3];
        ushort4 v0 = *(const ushort4*)(p2b + (size_t)s0 * 64 + lane * 4);
        ushort4 v1 = *(const ushort4*)(p2b + (size_t)s1 * 64 + lane * 4);
        ushort4 v2 = *(const ushort4*)(p2b + (size_t)s2i * 64 + lane * 4);
        ushort4 v3 = *(const ushort4*)(p2b + (size_t)s3 * 64 + lane * 4);
        p0 += bf2f(v0.x); p1 += bf2f(v0.y); p2 += bf2f(v0.z); p3 += bf2f(v0.w);
        q0 += bf2f(v1.x); q1 += bf2f(v1.y); q2 += bf2f(v1.z); q3 += bf2f(v1.w);
        r0 += bf2f(v2.x); r1 += bf2f(v2.y); r2 += bf2f(v2.z); r3 += bf2f(v2.w);
        t0 += bf2f(v3.x); t1 += bf2f(v3.y); t2 += bf2f(v3.z); t3 += bf2f(v3.w);
    }
    for (; e < end; ++e) {
        int s = ssrc[e];
        ushort4 v = *(const ushort4*)(p2b + (size_t)s * 64 + lane * 4);
        p0 += bf2f(v.x); p1 += bf2f(v.y); p2 += bf2f(v.z); p3 += bf2f(v.w);
    }
    float a0 = (p0 + q0) + (r0 + t0);
    float a1 = (p1 + q1) + (r1 + t1);
    float a2 = (p2 + q2) + (r2 + t2);
    float a3 = (p3 + q3) + (r3 + t3);
    float iv = invd[node];
    float4 sv = *(const float4*)(s2 + (size_t)node * 64 + lane * 4);
    float4 bv = *(const float4*)(b2 + lane * 4);
    f32x4 r;
    r[0] = sv.x + a0 * iv + bv.x;
    r[1] = sv.y + a1 * iv + bv.y;
    r[2] = sv.z + a2 * iv + bv.z;
    r[3] = sv.w + a3 * iv + bv.w;
    __builtin_nontemporal_store(r, (f32x4*)(h2a + (size_t)node * 64 + lane * 4));
    __builtin_nontemporal_store(r, (f32x4*)(h2b + (size_t)node * 64 + lane * 4));
}

static inline size_t align256(size_t x) { return (x + 255) & ~(size_t)255; }

extern "C" void kernel_launch(void* const* d_in, const int* in_sizes, int n_in,
                              void* d_out, int out_size, void* d_ws, size_t ws_size,
                              hipStream_t stream) {
    const float* x   = (const float*)d_in[0];
    const float* Ws1 = (const float*)d_in[1];
    const float* Wn1 = (const float*)d_in[2];
    const float* b1  = (const float*)d_in[3];
    const float* Ws2 = (const float*)d_in[4];
    const float* Wn2 = (const float*)d_in[5];
    const float* b2  = (const float*)d_in[6];
    const int* src   = (const int*)d_in[7];
    const int* dst   = (const int*)d_in[8];

    int E = in_sizes[7];
    int N = in_sizes[0] / NFEAT;

    float* out = (float*)d_out;
    float* h2a = out;                         // h2 (copy 1), N x 64
    float* h1  = out + (size_t)N * 64;        // h1, N x 128
    float* h1r = out + (size_t)N * 192;       // relu(h1), N x 128
    float* h2b = out + (size_t)N * 320;       // h2 (copy 2), N x 64

    char* ws = (char*)d_ws;
    size_t off = 0;
    int*   deg    = (int*)(ws + off);  off = align256(off + (size_t)4 * N);
    int*   offs   = (int*)(ws + off);  off = align256(off + (size_t)4 * (N + 1));
    int*   cursor = (int*)(ws + off);  off = align256(off + (size_t)4 * N);
    float* invd   = (float*)(ws + off); off = align256(off + (size_t)4 * N);
    int*   escan  = (int*)(ws + off);  off = align256(off + (size_t)4 * N);
    int*   bsum   = (int*)(ws + off);  off = align256(off + (size_t)4 * 1024);
    int*   ssrc   = (int*)(ws + off);  off = align256(off + (size_t)4 * E);
    unsigned short* wb1 = (unsigned short*)(ws + off); off = align256(off + 2 * 32768);
    unsigned short* wb2 = (unsigned short*)(ws + off); off = align256(off + 2 * 16384);
    unsigned short* xb = (unsigned short*)(ws + off);           // N*128 bf16
    off = align256(off + (size_t)N * NFEAT * 2);
    float* s2 = (float*)(ws + off);                             // N*64 f32 (own region)
    off = align256(off + (size_t)N * 64 * 4);
    unsigned short* p2b = (unsigned short*)(ws + off);          // N*64 bf16
    off = align256(off + (size_t)N * 64 * 2);

    int nb = (N + 1023) / 1024;
    int P = (N + 7) / 8;                      // nodes per XCD partition
    int C = (N * 32 + 255) / 256;             // cvt blocks in k_prep

    hipMemsetAsync(deg, 0, (size_t)4 * N, stream);
    k_deg<<<8 * 256, 256, 0, stream>>>(dst, deg, E, P);
    k_scan1<<<nb, 256, 0, stream>>>(deg, escan, bsum, N);
    k_scan2<<<1, 1024, 0, stream>>>(bsum, nb);
    k_scan3<<<nb, 256, 0, stream>>>(deg, escan, bsum, offs, cursor, invd, N);
    k_prep<<<C + 192, 256, 0, stream>>>(x, xb, Ws1, Wn1, wb1, Ws2, Wn2, wb2,
                                        N * 32, C);
    k_scatter<<<8 * 256, 256, 0, stream>>>(src, dst, cursor, ssrc, E, P);

    k_mmf<<<(N + 63) / 64, 256, 0, stream>>>(xb, offs, ssrc, invd, wb1, b1, wb2,
                                             h1, h1r, s2, p2b, N);
    k_agg2<<<(N + 15) / 16, 256, 0, stream>>>(p2b, offs, ssrc, invd, s2, b2, h2a, h2b, N);
}